// Round 1
// baseline (2377.412 us; speedup 1.0000x reference)
//
#include <hip/hip_runtime.h>
#include <math.h>

// GraphWaveNet forward, MI355X. Round 1: correctness-first fp32.
// Layouts:
//   h, g, gd : [B=16, C=32, t=13, N=1024]  (n contiguous)
//   adp      : [v=1024, w=1024]            (w contiguous)
//   skip_acc : [B, S=256, N]
//   y1       : [B, E=512, N]
//   out      : [B, N, O=12]
// Absolute-time indexing: layer i valid output times t in [t0_i, 12].

#define NBATCH 16
#define LLEN 13
#define NNODE 1024
#define RC 32
#define DC 32
#define SCH 256
#define ECH 512
#define OCH 12

// ---------------- adaptive adjacency: softmax(relu(E E^T), axis=1) ----------
__global__ void adp_kernel(const float* __restrict__ emb, float* __restrict__ adp) {
    int v = blockIdx.x;
    int tid = threadIdx.x;
    __shared__ float red[256];
    float ev[10];
#pragma unroll
    for (int k = 0; k < 10; ++k) ev[k] = emb[v * 10 + k];
    float sc[4];
#pragma unroll
    for (int j = 0; j < 4; ++j) {
        int w = tid + j * 256;
        float s = 0.f;
#pragma unroll
        for (int k = 0; k < 10; ++k) s += ev[k] * emb[w * 10 + k];
        sc[j] = fmaxf(s, 0.f);
    }
    float mx = fmaxf(fmaxf(sc[0], sc[1]), fmaxf(sc[2], sc[3]));
    red[tid] = mx;
    __syncthreads();
    for (int s = 128; s > 0; s >>= 1) {
        if (tid < s) red[tid] = fmaxf(red[tid], red[tid + s]);
        __syncthreads();
    }
    mx = red[0];
    __syncthreads();
    float e[4];
    float sum = 0.f;
#pragma unroll
    for (int j = 0; j < 4; ++j) { e[j] = expf(sc[j] - mx); sum += e[j]; }
    red[tid] = sum;
    __syncthreads();
    for (int s = 128; s > 0; s >>= 1) {
        if (tid < s) red[tid] += red[tid + s];
        __syncthreads();
    }
    float inv = 1.f / red[0];
#pragma unroll
    for (int j = 0; j < 4; ++j) adp[v * 1024 + tid + j * 256] = e[j] * inv;
}

// ---------------- start 1x1 conv: x[B,L,N,2] -> h[B,R,t,N] -------------------
__global__ void start_kernel(const float* __restrict__ x, const float* __restrict__ w,
                             const float* __restrict__ b, float* __restrict__ h) {
    int n = blockIdx.x * 256 + threadIdx.x;
    int t = blockIdx.y;
    int bb = blockIdx.z;
    float2 xv = *(const float2*)(x + (size_t)((bb * LLEN + t) * NNODE + n) * 2);
#pragma unroll
    for (int r = 0; r < RC; ++r) {
        h[((bb * RC + r) * LLEN + t) * NNODE + n] = w[r * 2] * xv.x + w[r * 2 + 1] * xv.y + b[r];
    }
}

// ---------------- TCN dilated conv + gating -> g -----------------------------
// conv[t] = w0 . h[t-d] + w1 . h[t] + b ; g = tanh(conv)*sigmoid(conv)
__global__ void tcn_kernel(const float* __restrict__ h, float* __restrict__ g,
                           const float* __restrict__ w, const float* __restrict__ bias,
                           int d, int t0) {
    __shared__ float sw0[32][32], sw1[32][32], sb[32];
    int tid = threadIdx.x;
    for (int idx = tid; idx < 1024; idx += 256) {
        int o = idx >> 5, c = idx & 31;
        sw0[o][c] = w[idx * 2];
        sw1[o][c] = w[idx * 2 + 1];
    }
    if (tid < 32) sb[tid] = bias[tid];
    __syncthreads();
    int n = blockIdx.x * 256 + tid;
    int t = t0 + blockIdx.y;
    int bb = blockIdx.z;
    const float* hbase = h + ((size_t)bb * DC * LLEN + t) * NNODE + n;
    float hp[32], hc[32];
#pragma unroll
    for (int c = 0; c < 32; ++c) {
        hp[c] = hbase[(c * LLEN - d) * NNODE];
        hc[c] = hbase[(c * LLEN) * NNODE];
    }
    for (int o = 0; o < 32; ++o) {
        float a = sb[o];
#pragma unroll
        for (int c = 0; c < 32; ++c) a += sw0[o][c] * hp[c] + sw1[o][c] * hc[c];
        float gt = tanhf(a) * (1.f / (1.f + expf(-a)));
        g[((bb * DC + o) * LLEN + t) * NNODE + n] = gt;
    }
}

// ---------------- skip contribution at t=12 ---------------------------------
__global__ void skip_kernel(const float* __restrict__ g, float* __restrict__ skip_acc,
                            const float* __restrict__ w, const float* __restrict__ bias,
                            int first) {
    __shared__ float sw[256][32];
    int tid = threadIdx.x;
    for (int idx = tid; idx < 8192; idx += 256) sw[idx >> 5][idx & 31] = w[idx];
    __syncthreads();
    int n = blockIdx.x * 256 + tid;
    int bb = blockIdx.y;
    float gv[32];
#pragma unroll
    for (int c = 0; c < 32; ++c) gv[c] = g[((bb * DC + c) * LLEN + 12) * NNODE + n];
    for (int s = 0; s < 256; ++s) {
        float a = bias[s];
#pragma unroll
        for (int c = 0; c < 32; ++c) a += sw[s][c] * gv[c];
        int oi = (bb * SCH + s) * NNODE + n;
        skip_acc[oi] = first ? a : (skip_acc[oi] + a);
    }
}

// ---------------- graph diffusion GEMM: gd[m,w] = sum_v g[m,v]*adp[v,w] ------
// rows m enumerate (bc, t) with t in [t0, t0+Lt); M = 512*Lt (divisible by 64)
__global__ void diff_gemm(const float* __restrict__ g, const float* __restrict__ adp,
                          float* __restrict__ gd, int t0, int Lt) {
    __shared__ float As[16][68];
    __shared__ float Bs[16][64];
    int tid = threadIdx.x;
    int w0 = blockIdx.x * 64;
    int m0 = blockIdx.y * 64;
    int arow = tid >> 2, akg = (tid & 3) * 4;
    int brow = tid >> 4, bcol = (tid & 15) * 4;
    int tx = tid & 15, ty = tid >> 4;
    int am = m0 + arow;
    int abc = am / Lt;
    int att = am - abc * Lt;
    const float* Arow = g + ((abc * LLEN) + t0 + att) * NNODE;
    float acc[4][4] = {{0.f}};
    for (int kk = 0; kk < 1024; kk += 16) {
        float4 av = *(const float4*)(Arow + kk + akg);
        float4 bv = *(const float4*)(adp + (kk + brow) * 1024 + w0 + bcol);
        __syncthreads();
        As[akg + 0][arow] = av.x;
        As[akg + 1][arow] = av.y;
        As[akg + 2][arow] = av.z;
        As[akg + 3][arow] = av.w;
        *(float4*)&Bs[brow][bcol] = bv;
        __syncthreads();
#pragma unroll
        for (int k = 0; k < 16; ++k) {
            float4 a = *(const float4*)&As[k][ty * 4];
            float4 b = *(const float4*)&Bs[k][tx * 4];
            acc[0][0] += a.x * b.x; acc[0][1] += a.x * b.y; acc[0][2] += a.x * b.z; acc[0][3] += a.x * b.w;
            acc[1][0] += a.y * b.x; acc[1][1] += a.y * b.y; acc[1][2] += a.y * b.z; acc[1][3] += a.y * b.w;
            acc[2][0] += a.z * b.x; acc[2][1] += a.z * b.y; acc[2][2] += a.z * b.z; acc[2][3] += a.z * b.w;
            acc[3][0] += a.w * b.x; acc[3][1] += a.w * b.y; acc[3][2] += a.w * b.z; acc[3][3] += a.w * b.w;
        }
    }
#pragma unroll
    for (int i = 0; i < 4; ++i) {
        int m = m0 + ty * 4 + i;
        int bc = m / Lt;
        int tt = m - bc * Lt;
        float* Crow = gd + ((bc * LLEN) + t0 + tt) * NNODE;
        *(float4*)(Crow + w0 + tx * 4) = make_float4(acc[i][0], acc[i][1], acc[i][2], acc[i][3]);
    }
}

// ---------------- gcn 1x1 conv + relu + residual + BN (in-place on h) -------
__global__ void gcn_kernel(const float* __restrict__ gd, float* __restrict__ h,
                           const float* __restrict__ w, const float* __restrict__ bias,
                           const float* __restrict__ gamma, const float* __restrict__ beta,
                           const float* __restrict__ mean, const float* __restrict__ var,
                           int t0) {
    __shared__ float sw[32][32], sb[32], sinv[32], sbeta[32], smean[32];
    int tid = threadIdx.x;
    for (int idx = tid; idx < 1024; idx += 256) sw[idx >> 5][idx & 31] = w[idx];
    if (tid < 32) {
        sb[tid] = bias[tid];
        sinv[tid] = gamma[tid] * rsqrtf(var[tid] + 1e-5f);
        sbeta[tid] = beta[tid];
        smean[tid] = mean[tid];
    }
    __syncthreads();
    int n = blockIdx.x * 256 + tid;
    int t = t0 + blockIdx.y;
    int bb = blockIdx.z;
    float gv[32];
#pragma unroll
    for (int c = 0; c < 32; ++c) gv[c] = gd[((bb * DC + c) * LLEN + t) * NNODE + n];
    for (int r = 0; r < 32; ++r) {
        float a = sb[r];
#pragma unroll
        for (int c = 0; c < 32; ++c) a += sw[r][c] * gv[c];
        int hi = ((bb * RC + r) * LLEN + t) * NNODE + n;
        float val = fmaxf(a, 0.f) + h[hi];
        h[hi] = (val - smean[r]) * sinv[r] + sbeta[r];
    }
}

// ---------------- end1 GEMM: y1[b,e,n] = relu(W1 @ relu(skip[b]) + b1) ------
__global__ void end1_gemm(const float* __restrict__ skip, const float* __restrict__ w1,
                          const float* __restrict__ b1, float* __restrict__ y1) {
    __shared__ float As[16][68];
    __shared__ float Bs[16][64];
    int tid = threadIdx.x;
    int e0 = blockIdx.x * 64;
    int n0 = blockIdx.y * 64;
    int bb = blockIdx.z;
    int arow = tid >> 2, akg = (tid & 3) * 4;
    int brow = tid >> 4, bcol = (tid & 15) * 4;
    int tx = tid & 15, ty = tid >> 4;
    float acc[4][4] = {{0.f}};
    for (int kk = 0; kk < 256; kk += 16) {
        float4 av = *(const float4*)(w1 + (e0 + arow) * 256 + kk + akg);
        float4 bv = *(const float4*)(skip + ((size_t)bb * SCH + kk + brow) * NNODE + n0 + bcol);
        bv.x = fmaxf(bv.x, 0.f); bv.y = fmaxf(bv.y, 0.f);
        bv.z = fmaxf(bv.z, 0.f); bv.w = fmaxf(bv.w, 0.f);
        __syncthreads();
        As[akg + 0][arow] = av.x;
        As[akg + 1][arow] = av.y;
        As[akg + 2][arow] = av.z;
        As[akg + 3][arow] = av.w;
        *(float4*)&Bs[brow][bcol] = bv;
        __syncthreads();
#pragma unroll
        for (int k = 0; k < 16; ++k) {
            float4 a = *(const float4*)&As[k][ty * 4];
            float4 b = *(const float4*)&Bs[k][tx * 4];
            acc[0][0] += a.x * b.x; acc[0][1] += a.x * b.y; acc[0][2] += a.x * b.z; acc[0][3] += a.x * b.w;
            acc[1][0] += a.y * b.x; acc[1][1] += a.y * b.y; acc[1][2] += a.y * b.z; acc[1][3] += a.y * b.w;
            acc[2][0] += a.z * b.x; acc[2][1] += a.z * b.y; acc[2][2] += a.z * b.z; acc[2][3] += a.z * b.w;
            acc[3][0] += a.w * b.x; acc[3][1] += a.w * b.y; acc[3][2] += a.w * b.z; acc[3][3] += a.w * b.w;
        }
    }
#pragma unroll
    for (int i = 0; i < 4; ++i) {
        int e = e0 + ty * 4 + i;
        float bv1 = b1[e];
        float4 o;
        o.x = fmaxf(acc[i][0] + bv1, 0.f);
        o.y = fmaxf(acc[i][1] + bv1, 0.f);
        o.z = fmaxf(acc[i][2] + bv1, 0.f);
        o.w = fmaxf(acc[i][3] + bv1, 0.f);
        *(float4*)(y1 + ((size_t)bb * ECH + e) * NNODE + n0 + tx * 4) = o;
    }
}

// ---------------- end2: out[b,n,o] = W2 @ y1 + b2 ---------------------------
__global__ void end2_kernel(const float* __restrict__ y1, const float* __restrict__ w2,
                            const float* __restrict__ b2, float* __restrict__ out) {
    __shared__ float sw[12][512];
    int tid = threadIdx.x;
    for (int idx = tid; idx < 6144; idx += 256) sw[idx >> 9][idx & 511] = w2[idx];
    __syncthreads();
    int n = blockIdx.x * 256 + tid;
    int bb = blockIdx.y;
    float acc[12];
#pragma unroll
    for (int o = 0; o < 12; ++o) acc[o] = b2[o];
    for (int e = 0; e < 512; ++e) {
        float y = y1[((size_t)bb * ECH + e) * NNODE + n];
#pragma unroll
        for (int o = 0; o < 12; ++o) acc[o] += sw[o][e] * y;
    }
#pragma unroll
    for (int o = 0; o < 12; ++o) out[((size_t)bb * NNODE + n) * OCH + o] = acc[o];
}

extern "C" void kernel_launch(void* const* d_in, const int* in_sizes, int n_in,
                              void* d_out, int out_size, void* d_ws, size_t ws_size,
                              hipStream_t stream) {
    const float* x       = (const float*)d_in[0];
    const float* emb     = (const float*)d_in[1];
    const float* start_w = (const float*)d_in[2];
    const float* start_b = (const float*)d_in[3];
    const float* tcn_w   = (const float*)d_in[4];
    const float* tcn_b   = (const float*)d_in[5];
    const float* skip_w  = (const float*)d_in[6];
    const float* skip_b  = (const float*)d_in[7];
    const float* gcn_w   = (const float*)d_in[8];
    const float* gcn_b   = (const float*)d_in[9];
    const float* bn_g    = (const float*)d_in[10];
    const float* bn_b    = (const float*)d_in[11];
    const float* bn_m    = (const float*)d_in[12];
    const float* bn_v    = (const float*)d_in[13];
    const float* e1w     = (const float*)d_in[14];
    const float* e1b     = (const float*)d_in[15];
    const float* e2w     = (const float*)d_in[16];
    const float* e2b     = (const float*)d_in[17];
    float* out = (float*)d_out;

    char* wsb = (char*)d_ws;
    // sizes (bytes): adp 4MB; h/g/gd 16*32*13*1024*4 = 27262976 each;
    // skip 16777216; y1 33554432. total ~136.3 MB
    float* adp  = (float*)(wsb);
    float* h    = (float*)(wsb + 4194304u);
    float* g    = (float*)(wsb + 4194304u + 27262976u);
    float* gd   = (float*)(wsb + 4194304u + 2u * 27262976u);
    float* skip = (float*)(wsb + 4194304u + 3u * 27262976u);
    float* y1   = (float*)(wsb + 4194304u + 3u * 27262976u + 16777216u);

    adp_kernel<<<dim3(1024), dim3(256), 0, stream>>>(emb, adp);
    start_kernel<<<dim3(4, 13, 16), dim3(256), 0, stream>>>(x, start_w, start_b, h);

    const int dil[8] = {1, 2, 1, 2, 1, 2, 1, 2};
    const int t0s[8] = {1, 3, 4, 6, 7, 9, 10, 12};
    for (int i = 0; i < 8; ++i) {
        int d = dil[i];
        int t0 = t0s[i];
        int Lt = 13 - t0;
        tcn_kernel<<<dim3(4, Lt, 16), dim3(256), 0, stream>>>(
            h, g, tcn_w + i * 2048, tcn_b + i * 32, d, t0);
        skip_kernel<<<dim3(4, 16), dim3(256), 0, stream>>>(
            g, skip, skip_w + i * 8192, skip_b + i * 256, i == 0 ? 1 : 0);
        diff_gemm<<<dim3(16, 8 * Lt), dim3(256), 0, stream>>>(g, adp, gd, t0, Lt);
        gcn_kernel<<<dim3(4, Lt, 16), dim3(256), 0, stream>>>(
            gd, h, gcn_w + i * 1024, gcn_b + i * 32,
            bn_g + i * 32, bn_b + i * 32, bn_m + i * 32, bn_v + i * 32, t0);
    }

    end1_gemm<<<dim3(8, 16, 16), dim3(256), 0, stream>>>(skip, e1w, e1b, y1);
    end2_kernel<<<dim3(4, 16), dim3(256), 0, stream>>>(y1, e2w, e2b, out);
}

// Round 2
// 1491.809 us; speedup vs baseline: 1.5936x; 1.5936x over previous
//
#include <hip/hip_runtime.h>
#include <math.h>

// GraphWaveNet forward, MI355X. Round 2: bf16 MFMA diffusion + tcn/skip fusion.
// Layouts:
//   h  : [B=16, C=32, t=13, N=1024] fp32
//   g  : [B*C, t=13, N=1024] bf16 (MFMA A operand, K-major over n)
//   adpT : [w=1024][v=1024] bf16 (MFMA B operand, K-major over v)
//   gd : [B*C, t=13, N=1024] fp32
//   skip_acc : [B, S=256, N] fp32 ; y1 : [B, E=512, N] fp32 ; out [B,N,O]

#define NBATCH 16
#define LLEN 13
#define NNODE 1024
#define RC 32
#define DC 32
#define SCH 256
#define ECH 512
#define OCH 12

typedef __attribute__((ext_vector_type(8))) short bf16x8;
typedef __attribute__((ext_vector_type(4))) float f32x4;

#define GLOAD16(gp, lp) __builtin_amdgcn_global_load_lds( \
    (const __attribute__((address_space(1))) void*)(gp), \
    (__attribute__((address_space(3))) void*)(lp), 16, 0, 0)

static __device__ inline short f2bf(float x) {
    union { float f; unsigned u; } v; v.f = x;
    unsigned r = v.u + 0x7FFFu + ((v.u >> 16) & 1u);
    return (short)(r >> 16);
}

// ---------------- adjacency stats: per-row (v) max and 1/sum ----------------
__global__ void adp_stats(const float* __restrict__ emb, float* __restrict__ mx,
                          float* __restrict__ inv) {
    int v = blockIdx.x;
    int tid = threadIdx.x;
    __shared__ float red[256];
    float ev[10];
#pragma unroll
    for (int k = 0; k < 10; ++k) ev[k] = emb[v * 10 + k];
    float sc[4];
#pragma unroll
    for (int j = 0; j < 4; ++j) {
        int w = tid + j * 256;
        float s = 0.f;
#pragma unroll
        for (int k = 0; k < 10; ++k) s += ev[k] * emb[w * 10 + k];
        sc[j] = fmaxf(s, 0.f);
    }
    float m = fmaxf(fmaxf(sc[0], sc[1]), fmaxf(sc[2], sc[3]));
    red[tid] = m;
    __syncthreads();
    for (int s = 128; s > 0; s >>= 1) {
        if (tid < s) red[tid] = fmaxf(red[tid], red[tid + s]);
        __syncthreads();
    }
    m = red[0];
    __syncthreads();
    float sum = 0.f;
#pragma unroll
    for (int j = 0; j < 4; ++j) sum += expf(sc[j] - m);
    red[tid] = sum;
    __syncthreads();
    for (int s = 128; s > 0; s >>= 1) {
        if (tid < s) red[tid] += red[tid + s];
        __syncthreads();
    }
    if (tid == 0) { mx[v] = m; inv[v] = 1.f / red[0]; }
}

// ---------------- adpT[w][v] = softmax_row_v(relu(E E^T))[v][w], bf16 -------
__global__ void adpT_kernel(const float* __restrict__ emb, const float* __restrict__ mx,
                            const float* __restrict__ inv, short* __restrict__ adpT) {
    int w = blockIdx.x;
    int tid = threadIdx.x;
    __shared__ float ew[10];
    if (tid < 10) ew[tid] = emb[w * 10 + tid];
    __syncthreads();
#pragma unroll
    for (int j = 0; j < 4; ++j) {
        int v = tid + j * 256;
        float s = 0.f;
#pragma unroll
        for (int k = 0; k < 10; ++k) s += ew[k] * emb[v * 10 + k];
        s = fmaxf(s, 0.f);
        float val = expf(s - mx[v]) * inv[v];
        adpT[w * 1024 + v] = f2bf(val);
    }
}

// ---------------- start 1x1 conv: x[B,L,N,2] -> h[B,R,t,N] -------------------
__global__ void start_kernel(const float* __restrict__ x, const float* __restrict__ w,
                             const float* __restrict__ b, float* __restrict__ h) {
    int n = blockIdx.x * 256 + threadIdx.x;
    int t = blockIdx.y;
    int bb = blockIdx.z;
    float2 xv = *(const float2*)(x + (size_t)((bb * LLEN + t) * NNODE + n) * 2);
#pragma unroll
    for (int r = 0; r < RC; ++r) {
        h[((bb * RC + r) * LLEN + t) * NNODE + n] = w[r * 2] * xv.x + w[r * 2 + 1] * xv.y + b[r];
    }
}

// ---------------- TCN dilated conv + gating -> g (bf16); fused skip at t=12 --
__global__ void tcn_skip_kernel(const float* __restrict__ h, short* __restrict__ g,
                                float* __restrict__ skip_acc,
                                const float* __restrict__ w, const float* __restrict__ bias,
                                const float* __restrict__ sw_g, const float* __restrict__ sb_g,
                                int d, int t0, int Lt, int first) {
    __shared__ float sw0[32][32], sw1[32][32], sb[32];
    __shared__ float ssw[256][32];
    int tid = threadIdx.x;
    int t = t0 + blockIdx.y;
    for (int idx = tid; idx < 1024; idx += 256) {
        int o = idx >> 5, c = idx & 31;
        sw0[o][c] = w[idx * 2];
        sw1[o][c] = w[idx * 2 + 1];
    }
    if (tid < 32) sb[tid] = bias[tid];
    if (t == 12) {
        for (int idx = tid; idx < 8192; idx += 256) ssw[idx >> 5][idx & 31] = sw_g[idx];
    }
    __syncthreads();
    int n = blockIdx.x * 256 + tid;
    int bb = blockIdx.z;
    const float* hbase = h + ((size_t)bb * RC * LLEN + t) * NNODE + n;
    float hp[32], hc[32];
#pragma unroll
    for (int c = 0; c < 32; ++c) {
        hp[c] = hbase[(c * LLEN - d) * NNODE];
        hc[c] = hbase[(c * LLEN) * NNODE];
    }
    float gv[32];
    for (int o = 0; o < 32; ++o) {
        float a = sb[o];
#pragma unroll
        for (int c = 0; c < 32; ++c) a += sw0[o][c] * hp[c] + sw1[o][c] * hc[c];
        float gt = tanhf(a) * (1.f / (1.f + expf(-a)));
        gv[o] = gt;
        g[((bb * DC + o) * LLEN + t) * NNODE + n] = f2bf(gt);
    }
    if (t == 12) {
        float* so = skip_acc + ((size_t)bb * SCH << 10) + n;
        for (int s = 0; s < 256; ++s) {
            float a = sb_g[s];
#pragma unroll
            for (int c = 0; c < 32; ++c) a += ssw[s][c] * gv[c];
            if (first) so[s << 10] = a;
            else so[s << 10] += a;
        }
    }
}

// ---------------- diffusion GEMM (bf16 MFMA): gd[m,w] = sum_v g[m,v]*adp[v,w] --
// A = g rows (bc,t), K-major over v. B = adpT rows w, K-major over v.
// 128x128 tile, BK=32, 4 waves, each wave 64x64 via 4x4 mfma_f32_16x16x32_bf16.
__global__ __launch_bounds__(256) void diff_mfma(const short* __restrict__ g,
                                                 const short* __restrict__ adpT,
                                                 float* __restrict__ gd,
                                                 int t0, int Lt) {
    __shared__ __align__(16) short As[128 * 32];
    __shared__ __align__(16) short Bs[128 * 32];
    int tid = threadIdx.x;
    int wave = tid >> 6, lane = tid & 63;
    int n0 = blockIdx.x * 128;
    int m0 = blockIdx.y * 128;

    // staging: chunk idx -> (row = idx>>2, col8 = (idx&3)*8); lds offset = idx*8 shorts
    int idx0 = wave * 128 + lane;
    int rowS0 = idx0 >> 2, colS0 = (idx0 & 3) * 8;
    int idx1 = idx0 + 64;
    int rowS1 = idx1 >> 2, colS1 = (idx1 & 3) * 8;
    int mg0 = m0 + rowS0, bc0 = mg0 / Lt, tt0 = mg0 - bc0 * Lt;
    const short* gA0 = g + ((size_t)(bc0 * LLEN + t0 + tt0) << 10) + colS0;
    int mg1 = m0 + rowS1, bc1 = mg1 / Lt, tt1 = mg1 - bc1 * Lt;
    const short* gA1 = g + ((size_t)(bc1 * LLEN + t0 + tt1) << 10) + colS1;
    const short* gB0 = adpT + ((size_t)(n0 + rowS0) << 10) + colS0;
    const short* gB1 = adpT + ((size_t)(n0 + rowS1) << 10) + colS1;
    short* ldsA0 = As + wave * 1024;
    short* ldsA1 = As + wave * 1024 + 512;
    short* ldsB0 = Bs + wave * 1024;
    short* ldsB1 = Bs + wave * 1024 + 512;

    int wm = (wave & 1) * 64, wn = (wave >> 1) * 64;
    int quad = lane >> 4, lrow = lane & 15;
    const short* pa = As + (wm + lrow) * 32 + quad * 8;
    const short* pb = Bs + (wn + lrow) * 32 + quad * 8;

    f32x4 acc[4][4] = {};
    for (int kk = 0; kk < 1024; kk += 32) {
        GLOAD16(gA0 + kk, ldsA0);
        GLOAD16(gA1 + kk, ldsA1);
        GLOAD16(gB0 + kk, ldsB0);
        GLOAD16(gB1 + kk, ldsB1);
        __syncthreads();
        bf16x8 a[4], b[4];
#pragma unroll
        for (int i = 0; i < 4; ++i) {
            a[i] = *(const bf16x8*)(pa + i * 16 * 32);
            b[i] = *(const bf16x8*)(pb + i * 16 * 32);
        }
#pragma unroll
        for (int mi = 0; mi < 4; ++mi)
#pragma unroll
            for (int ni = 0; ni < 4; ++ni)
                acc[mi][ni] = __builtin_amdgcn_mfma_f32_16x16x32_bf16(a[mi], b[ni], acc[mi][ni], 0, 0, 0);
        __syncthreads();
    }
    // C/D: col = lane&15, row = quad*4 + reg
#pragma unroll
    for (int mi = 0; mi < 4; ++mi) {
#pragma unroll
        for (int r = 0; r < 4; ++r) {
            int m = m0 + wm + mi * 16 + quad * 4 + r;
            int bc = m / Lt, tt = m - bc * Lt;
            float* crow = gd + ((size_t)(bc * LLEN + t0 + tt) << 10) + n0 + wn + lrow;
#pragma unroll
            for (int ni = 0; ni < 4; ++ni)
                crow[ni * 16] = acc[mi][ni][r];
        }
    }
}

// ---------------- gcn 1x1 conv + relu + residual + BN (in-place on h) -------
__global__ void gcn_kernel(const float* __restrict__ gd, float* __restrict__ h,
                           const float* __restrict__ w, const float* __restrict__ bias,
                           const float* __restrict__ gamma, const float* __restrict__ beta,
                           const float* __restrict__ mean, const float* __restrict__ var,
                           int t0) {
    __shared__ float sw[32][32], sb[32], sinv[32], sbeta[32], smean[32];
    int tid = threadIdx.x;
    for (int idx = tid; idx < 1024; idx += 256) sw[idx >> 5][idx & 31] = w[idx];
    if (tid < 32) {
        sb[tid] = bias[tid];
        sinv[tid] = gamma[tid] * rsqrtf(var[tid] + 1e-5f);
        sbeta[tid] = beta[tid];
        smean[tid] = mean[tid];
    }
    __syncthreads();
    int n = blockIdx.x * 256 + tid;
    int t = t0 + blockIdx.y;
    int bb = blockIdx.z;
    float gv[32];
#pragma unroll
    for (int c = 0; c < 32; ++c) gv[c] = gd[((bb * DC + c) * LLEN + t) * NNODE + n];
    for (int r = 0; r < 32; ++r) {
        float a = sb[r];
#pragma unroll
        for (int c = 0; c < 32; ++c) a += sw[r][c] * gv[c];
        int hi = ((bb * RC + r) * LLEN + t) * NNODE + n;
        float val = fmaxf(a, 0.f) + h[hi];
        h[hi] = (val - smean[r]) * sinv[r] + sbeta[r];
    }
}

// ---------------- end1 GEMM: y1[b,e,n] = relu(W1 @ relu(skip[b]) + b1) ------
__global__ void end1_gemm(const float* __restrict__ skip, const float* __restrict__ w1,
                          const float* __restrict__ b1, float* __restrict__ y1) {
    __shared__ float As[16][68];
    __shared__ float Bs[16][64];
    int tid = threadIdx.x;
    int e0 = blockIdx.x * 64;
    int n0 = blockIdx.y * 64;
    int bb = blockIdx.z;
    int arow = tid >> 2, akg = (tid & 3) * 4;
    int brow = tid >> 4, bcol = (tid & 15) * 4;
    int tx = tid & 15, ty = tid >> 4;
    float acc[4][4] = {{0.f}};
    for (int kk = 0; kk < 256; kk += 16) {
        float4 av = *(const float4*)(w1 + (e0 + arow) * 256 + kk + akg);
        float4 bv = *(const float4*)(skip + ((size_t)bb * SCH + kk + brow) * NNODE + n0 + bcol);
        bv.x = fmaxf(bv.x, 0.f); bv.y = fmaxf(bv.y, 0.f);
        bv.z = fmaxf(bv.z, 0.f); bv.w = fmaxf(bv.w, 0.f);
        __syncthreads();
        As[akg + 0][arow] = av.x;
        As[akg + 1][arow] = av.y;
        As[akg + 2][arow] = av.z;
        As[akg + 3][arow] = av.w;
        *(float4*)&Bs[brow][bcol] = bv;
        __syncthreads();
#pragma unroll
        for (int k = 0; k < 16; ++k) {
            float4 a = *(const float4*)&As[k][ty * 4];
            float4 b = *(const float4*)&Bs[k][tx * 4];
            acc[0][0] += a.x * b.x; acc[0][1] += a.x * b.y; acc[0][2] += a.x * b.z; acc[0][3] += a.x * b.w;
            acc[1][0] += a.y * b.x; acc[1][1] += a.y * b.y; acc[1][2] += a.y * b.z; acc[1][3] += a.y * b.w;
            acc[2][0] += a.z * b.x; acc[2][1] += a.z * b.y; acc[2][2] += a.z * b.z; acc[2][3] += a.z * b.w;
            acc[3][0] += a.w * b.x; acc[3][1] += a.w * b.y; acc[3][2] += a.w * b.z; acc[3][3] += a.w * b.w;
        }
    }
#pragma unroll
    for (int i = 0; i < 4; ++i) {
        int e = e0 + ty * 4 + i;
        float bv1 = b1[e];
        float4 o;
        o.x = fmaxf(acc[i][0] + bv1, 0.f);
        o.y = fmaxf(acc[i][1] + bv1, 0.f);
        o.z = fmaxf(acc[i][2] + bv1, 0.f);
        o.w = fmaxf(acc[i][3] + bv1, 0.f);
        *(float4*)(y1 + ((size_t)bb * ECH + e) * NNODE + n0 + tx * 4) = o;
    }
}

// ---------------- end2: out[b,n,o] = W2 @ y1 + b2 ---------------------------
__global__ void end2_kernel(const float* __restrict__ y1, const float* __restrict__ w2,
                            const float* __restrict__ b2, float* __restrict__ out) {
    __shared__ float sw[12][512];
    int tid = threadIdx.x;
    for (int idx = tid; idx < 6144; idx += 256) sw[idx >> 9][idx & 511] = w2[idx];
    __syncthreads();
    int n = blockIdx.x * 256 + tid;
    int bb = blockIdx.y;
    float acc[12];
#pragma unroll
    for (int o = 0; o < 12; ++o) acc[o] = b2[o];
    for (int e = 0; e < 512; ++e) {
        float y = y1[((size_t)bb * ECH + e) * NNODE + n];
#pragma unroll
        for (int o = 0; o < 12; ++o) acc[o] += sw[o][e] * y;
    }
#pragma unroll
    for (int o = 0; o < 12; ++o) out[((size_t)bb * NNODE + n) * OCH + o] = acc[o];
}

extern "C" void kernel_launch(void* const* d_in, const int* in_sizes, int n_in,
                              void* d_out, int out_size, void* d_ws, size_t ws_size,
                              hipStream_t stream) {
    const float* x       = (const float*)d_in[0];
    const float* emb     = (const float*)d_in[1];
    const float* start_w = (const float*)d_in[2];
    const float* start_b = (const float*)d_in[3];
    const float* tcn_w   = (const float*)d_in[4];
    const float* tcn_b   = (const float*)d_in[5];
    const float* skip_w  = (const float*)d_in[6];
    const float* skip_b  = (const float*)d_in[7];
    const float* gcn_w   = (const float*)d_in[8];
    const float* gcn_b   = (const float*)d_in[9];
    const float* bn_g    = (const float*)d_in[10];
    const float* bn_b    = (const float*)d_in[11];
    const float* bn_m    = (const float*)d_in[12];
    const float* bn_v    = (const float*)d_in[13];
    const float* e1w     = (const float*)d_in[14];
    const float* e1b     = (const float*)d_in[15];
    const float* e2w     = (const float*)d_in[16];
    const float* e2b     = (const float*)d_in[17];
    float* out = (float*)d_out;

    char* wsb = (char*)d_ws;
    short* adpT = (short*)(wsb);                         // 2,097,152
    float* mx   = (float*)(wsb + 2097152u);              // 4,096
    float* inv  = (float*)(wsb + 2101248u);              // 4,096
    float* h    = (float*)(wsb + 2105344u);              // 27,262,976
    short* g    = (short*)(wsb + 29368320u);             // 13,631,488
    float* gd   = (float*)(wsb + 42999808u);             // 27,262,976
    float* skip = (float*)(wsb + 70262784u);             // 16,777,216
    float* y1   = (float*)(wsb + 87040000u);             // 33,554,432

    adp_stats<<<dim3(1024), dim3(256), 0, stream>>>(emb, mx, inv);
    adpT_kernel<<<dim3(1024), dim3(256), 0, stream>>>(emb, mx, inv, adpT);
    start_kernel<<<dim3(4, 13, 16), dim3(256), 0, stream>>>(x, start_w, start_b, h);

    const int dil[8] = {1, 2, 1, 2, 1, 2, 1, 2};
    const int t0s[8] = {1, 3, 4, 6, 7, 9, 10, 12};
    for (int i = 0; i < 8; ++i) {
        int d = dil[i];
        int t0 = t0s[i];
        int Lt = 13 - t0;
        tcn_skip_kernel<<<dim3(4, Lt, 16), dim3(256), 0, stream>>>(
            h, g, skip, tcn_w + i * 2048, tcn_b + i * 32,
            skip_w + i * 8192, skip_b + i * 256, d, t0, Lt, i == 0 ? 1 : 0);
        diff_mfma<<<dim3(8, 4 * Lt), dim3(256), 0, stream>>>(g, adpT, gd, t0, Lt);
        gcn_kernel<<<dim3(4, Lt, 16), dim3(256), 0, stream>>>(
            gd, h, gcn_w + i * 1024, gcn_b + i * 32,
            bn_g + i * 32, bn_b + i * 32, bn_m + i * 32, bn_v + i * 32, t0);
    }

    end1_gemm<<<dim3(8, 16, 16), dim3(256), 0, stream>>>(skip, e1w, e1b, y1);
    end2_kernel<<<dim3(4, 16), dim3(256), 0, stream>>>(y1, e2w, e2b, out);
}

// Round 3
// 684.874 us; speedup vs baseline: 3.4713x; 2.1782x over previous
//
#include <hip/hip_runtime.h>
#include <math.h>

// GraphWaveNet forward, MI355X. Round 3:
//  - gcn channel-mix commuted into tcn (registers), gcn epilogue fused into diff MFMA
//  - skip telescoped into ONE end-of-net MFMA GEMM over concatenated layer outputs
//  - ends in bf16 MFMA
// Layouts:
//   h    : [B=16, C=32, t=13, N=1024] fp32 (residual stream, updated in place)
//   gm   : [bc=512, tt=Lt, N] bf16 compact per layer (mixed gated output)
//   g12  : [b, n, 256] bf16 (8 layers x 32 ch, t=12 gated outputs, K-major)
//   adpT : [w=1024][v=1024] bf16
//   skipT: [b][n][s=256] bf16 ; y1 : [b][e=512][n] bf16 ; out [B,N,O] fp32

#define NBATCH 16
#define LLEN 13
#define NNODE 1024

typedef __attribute__((ext_vector_type(8))) short bf16x8;
typedef __attribute__((ext_vector_type(4))) float f32x4;

#define GLOAD16(gp, lp) __builtin_amdgcn_global_load_lds( \
    (const __attribute__((address_space(1))) void*)(gp), \
    (__attribute__((address_space(3))) void*)(lp), 16, 0, 0)

static __device__ inline short f2bf(float x) {
    union { float f; unsigned u; } v; v.f = x;
    unsigned r = v.u + 0x7FFFu + ((v.u >> 16) & 1u);
    return (short)(r >> 16);
}
static __device__ inline float bf2f(short x) {
    union { unsigned u; float f; } v; v.u = ((unsigned)(unsigned short)x) << 16;
    return v.f;
}

// ---------------- adjacency stats: per-row (v) max and 1/sum ----------------
__global__ void adp_stats(const float* __restrict__ emb, float* __restrict__ mx,
                          float* __restrict__ inv) {
    int v = blockIdx.x;
    int tid = threadIdx.x;
    __shared__ float red[256];
    float ev[10];
#pragma unroll
    for (int k = 0; k < 10; ++k) ev[k] = emb[v * 10 + k];
    float sc[4];
#pragma unroll
    for (int j = 0; j < 4; ++j) {
        int w = tid + j * 256;
        float s = 0.f;
#pragma unroll
        for (int k = 0; k < 10; ++k) s += ev[k] * emb[w * 10 + k];
        sc[j] = fmaxf(s, 0.f);
    }
    float m = fmaxf(fmaxf(sc[0], sc[1]), fmaxf(sc[2], sc[3]));
    red[tid] = m;
    __syncthreads();
    for (int s = 128; s > 0; s >>= 1) {
        if (tid < s) red[tid] = fmaxf(red[tid], red[tid + s]);
        __syncthreads();
    }
    m = red[0];
    __syncthreads();
    float sum = 0.f;
#pragma unroll
    for (int j = 0; j < 4; ++j) sum += __expf(sc[j] - m);
    red[tid] = sum;
    __syncthreads();
    for (int s = 128; s > 0; s >>= 1) {
        if (tid < s) red[tid] += red[tid + s];
        __syncthreads();
    }
    if (tid == 0) { mx[v] = m; inv[v] = 1.f / red[0]; }
}

// ---------------- adpT[w][v] = softmax_v(relu(E E^T))[v][w] bf16 ------------
__global__ void adpT_kernel(const float* __restrict__ emb, const float* __restrict__ mx,
                            const float* __restrict__ inv, short* __restrict__ adpT) {
    int w = blockIdx.x;
    int tid = threadIdx.x;
    __shared__ float ew[10];
    if (tid < 10) ew[tid] = emb[w * 10 + tid];
    __syncthreads();
#pragma unroll
    for (int j = 0; j < 4; ++j) {
        int v = tid + j * 256;
        float s = 0.f;
#pragma unroll
        for (int k = 0; k < 10; ++k) s += ew[k] * emb[v * 10 + k];
        s = fmaxf(s, 0.f);
        adpT[w * 1024 + v] = f2bf(__expf(s - mx[v]) * inv[v]);
    }
}

// ---------------- start 1x1 conv: x[B,L,N,2] -> h[B,R,t,N] fp32 -------------
__global__ void start_kernel(const float* __restrict__ x, const float* __restrict__ w,
                             const float* __restrict__ b, float* __restrict__ h) {
    int n = blockIdx.x * 256 + threadIdx.x;
    int t = blockIdx.y;
    int bb = blockIdx.z;
    float2 xv = *(const float2*)(x + (size_t)((bb * LLEN + t) * NNODE + n) * 2);
#pragma unroll
    for (int r = 0; r < 32; ++r) {
        h[((bb * 32 + r) * LLEN + t) * NNODE + n] = w[r * 2] * xv.x + w[r * 2 + 1] * xv.y + b[r];
    }
}

// ---------------- weight repack: W_cat/sb_cat (skip) + e1w bf16 -------------
__global__ void repack_kernel(const float* __restrict__ skip_w, const float* __restrict__ skip_b,
                              const float* __restrict__ e1w, short* __restrict__ wcat,
                              float* __restrict__ sbcat, short* __restrict__ e1wb) {
    int idx = blockIdx.x * 256 + threadIdx.x;
    if (idx < 65536) {
        int s = idx >> 8, k = idx & 255, i = k >> 5, c = k & 31;
        wcat[idx] = f2bf(skip_w[(i * 256 + s) * 32 + c]);
    } else {
        int j = idx - 65536;
        e1wb[j] = f2bf(e1w[j]);
    }
    if (idx < 256) {
        float s = 0.f;
#pragma unroll
        for (int i = 0; i < 8; ++i) s += skip_b[i * 256 + idx];
        sbcat[idx] = s;
    }
}

// ---------------- TCN conv + gating + gcn channel-mix -> gm bf16 -------------
// also stashes raw gated output at t==12 into g12[b][n][li*32 + c]
__global__ void tcn_mix_kernel(const float* __restrict__ h, short* __restrict__ gm,
                               short* __restrict__ g12,
                               const float* __restrict__ w, const float* __restrict__ bias,
                               const float* __restrict__ gcnw,
                               int d, int t0, int Lt, int li) {
    __shared__ float sw0[32][32], sw1[32][32], sgw[32][32], sb[32];
    int tid = threadIdx.x;
    for (int idx = tid; idx < 1024; idx += 256) {
        int o = idx >> 5, c = idx & 31;
        sw0[o][c] = w[idx * 2];
        sw1[o][c] = w[idx * 2 + 1];
        sgw[o][c] = gcnw[idx];
    }
    if (tid < 32) sb[tid] = bias[tid];
    __syncthreads();
    int n = blockIdx.x * 256 + tid;
    int tt = blockIdx.y;
    int t = t0 + tt;
    int bb = blockIdx.z;
    const float* hb = h + (((size_t)(bb * 32 * LLEN + t)) << 10) + n;
    float hp[32], hc[32];
#pragma unroll
    for (int c = 0; c < 32; ++c) {
        hp[c] = hb[(size_t)((c * LLEN - d) << 10)];
        hc[c] = hb[(size_t)((c * LLEN) << 10)];
    }
    float gv[32];
    for (int o = 0; o < 32; ++o) {
        float a = sb[o];
#pragma unroll
        for (int c = 0; c < 32; ++c) a += sw0[o][c] * hp[c] + sw1[o][c] * hc[c];
        a = fminf(fmaxf(a, -25.f), 25.f);
        float e = __expf(-a);
        float e2 = e * e;
        gv[o] = (1.f - e2) / ((1.f + e2) * (1.f + e));  // tanh(a)*sigmoid(a)
    }
    if (t == 12) {
        short* gp = g12 + (((size_t)(bb << 10) + n) << 8) + li * 32;
#pragma unroll
        for (int c = 0; c < 32; ++c) gp[c] = f2bf(gv[c]);
    }
    // channel mix: gm[o] = sum_c gcn_w[o][c] * gv[c]
    for (int o = 0; o < 32; ++o) {
        float a = 0.f;
#pragma unroll
        for (int c = 0; c < 32; ++c) a += sgw[o][c] * gv[c];
        gm[(((size_t)((bb * 32 + o) * Lt + tt)) << 10) + n] = f2bf(a);
    }
}

// ---------------- diffusion MFMA + fused gcn epilogue (bias,relu,res,BN) -----
// C[m][w] = sum_v gm[m][v] * adpT[w][v]; m = bc*Lt + tt (compact)
// h[bc, t0+tt, w] = BN( relu(C + gcn_b[c]) + h_old )
__global__ __launch_bounds__(256) void diff_fused(const short* __restrict__ gm,
                                                  const short* __restrict__ adpT,
                                                  float* __restrict__ h,
                                                  const float* __restrict__ gb,
                                                  const float* __restrict__ bng,
                                                  const float* __restrict__ bnb,
                                                  const float* __restrict__ bnm,
                                                  const float* __restrict__ bnv,
                                                  int t0, int Lt) {
    __shared__ __align__(16) short As[128 * 32];
    __shared__ __align__(16) short Bs[128 * 32];
    __shared__ float sgb[32], sinv[32], smean[32], sbeta[32];
    int tid = threadIdx.x;
    int wave = tid >> 6, lane = tid & 63;
    int n0 = blockIdx.x * 128;
    int m0 = blockIdx.y * 128;
    if (tid < 32) {
        sgb[tid] = gb[tid];
        sinv[tid] = bng[tid] * rsqrtf(bnv[tid] + 1e-5f);
        smean[tid] = bnm[tid];
        sbeta[tid] = bnb[tid];
    }

    int idx0 = wave * 128 + lane;
    int rowS0 = idx0 >> 2, colS0 = (idx0 & 3) * 8;
    int idx1 = idx0 + 64;
    int rowS1 = idx1 >> 2, colS1 = (idx1 & 3) * 8;
    const short* gA0 = gm + (((size_t)(m0 + rowS0)) << 10) + colS0;
    const short* gA1 = gm + (((size_t)(m0 + rowS1)) << 10) + colS1;
    const short* gB0 = adpT + (((size_t)(n0 + rowS0)) << 10) + colS0;
    const short* gB1 = adpT + (((size_t)(n0 + rowS1)) << 10) + colS1;
    short* ldsA0 = As + wave * 1024;
    short* ldsA1 = As + wave * 1024 + 512;
    short* ldsB0 = Bs + wave * 1024;
    short* ldsB1 = Bs + wave * 1024 + 512;

    int wm = (wave & 1) * 64, wn = (wave >> 1) * 64;
    int quad = lane >> 4, lrow = lane & 15;
    const short* pa = As + (wm + lrow) * 32 + quad * 8;
    const short* pb = Bs + (wn + lrow) * 32 + quad * 8;

    f32x4 acc[4][4] = {};
    for (int kk = 0; kk < 1024; kk += 32) {
        GLOAD16(gA0 + kk, ldsA0);
        GLOAD16(gA1 + kk, ldsA1);
        GLOAD16(gB0 + kk, ldsB0);
        GLOAD16(gB1 + kk, ldsB1);
        __syncthreads();
        bf16x8 a[4], b[4];
#pragma unroll
        for (int i = 0; i < 4; ++i) {
            a[i] = *(const bf16x8*)(pa + i * 16 * 32);
            b[i] = *(const bf16x8*)(pb + i * 16 * 32);
        }
#pragma unroll
        for (int mi = 0; mi < 4; ++mi)
#pragma unroll
            for (int ni = 0; ni < 4; ++ni)
                acc[mi][ni] = __builtin_amdgcn_mfma_f32_16x16x32_bf16(a[mi], b[ni], acc[mi][ni], 0, 0, 0);
        __syncthreads();
    }
    // epilogue: C/D col = lane&15, row = quad*4 + reg
#pragma unroll
    for (int mi = 0; mi < 4; ++mi) {
#pragma unroll
        for (int r = 0; r < 4; ++r) {
            int m = m0 + wm + mi * 16 + quad * 4 + r;
            unsigned bc = (unsigned)m / (unsigned)Lt;
            int tt = m - (int)bc * Lt;
            int c = bc & 31;
            float invv = sinv[c], meanv = smean[c], betav = sbeta[c], gbv = sgb[c];
            float* crow = h + (((size_t)(bc * LLEN + t0 + tt)) << 10) + n0 + wn + lrow;
#pragma unroll
            for (int ni = 0; ni < 4; ++ni) {
                float v = fmaxf(acc[mi][ni][r] + gbv, 0.f) + crow[ni * 16];
                crow[ni * 16] = (v - meanv) * invv + betav;
            }
        }
    }
}

// ---------------- skip GEMM: skipT[b][n][s] = relu(Wcat @ g12 + sbcat) bf16 --
__global__ __launch_bounds__(256) void skip_mfma(const short* __restrict__ g12,
                                                 const short* __restrict__ wcat,
                                                 const float* __restrict__ sbcat,
                                                 short* __restrict__ skipT) {
    __shared__ __align__(16) short As[128 * 32];
    __shared__ __align__(16) short Bs[128 * 32];
    int tid = threadIdx.x;
    int wave = tid >> 6, lane = tid & 63;
    int s0 = blockIdx.x * 128;
    int m0 = blockIdx.y * 128;   // n rows
    int b = blockIdx.z;

    int idx0 = wave * 128 + lane;
    int rowS0 = idx0 >> 2, colS0 = (idx0 & 3) * 8;
    int idx1 = idx0 + 64;
    int rowS1 = idx1 >> 2, colS1 = (idx1 & 3) * 8;
    const short* gA0 = g12 + (((size_t)((b << 10) + m0 + rowS0)) << 8) + colS0;
    const short* gA1 = g12 + (((size_t)((b << 10) + m0 + rowS1)) << 8) + colS1;
    const short* gB0 = wcat + ((size_t)(s0 + rowS0) << 8) + colS0;
    const short* gB1 = wcat + ((size_t)(s0 + rowS1) << 8) + colS1;
    short* ldsA0 = As + wave * 1024;
    short* ldsA1 = As + wave * 1024 + 512;
    short* ldsB0 = Bs + wave * 1024;
    short* ldsB1 = Bs + wave * 1024 + 512;

    int wm = (wave & 1) * 64, wn = (wave >> 1) * 64;
    int quad = lane >> 4, lrow = lane & 15;
    const short* pa = As + (wm + lrow) * 32 + quad * 8;
    const short* pb = Bs + (wn + lrow) * 32 + quad * 8;

    f32x4 acc[4][4] = {};
    for (int kk = 0; kk < 256; kk += 32) {
        GLOAD16(gA0 + kk, ldsA0);
        GLOAD16(gA1 + kk, ldsA1);
        GLOAD16(gB0 + kk, ldsB0);
        GLOAD16(gB1 + kk, ldsB1);
        __syncthreads();
        bf16x8 a[4], bfr[4];
#pragma unroll
        for (int i = 0; i < 4; ++i) {
            a[i] = *(const bf16x8*)(pa + i * 16 * 32);
            bfr[i] = *(const bf16x8*)(pb + i * 16 * 32);
        }
#pragma unroll
        for (int mi = 0; mi < 4; ++mi)
#pragma unroll
            for (int ni = 0; ni < 4; ++ni)
                acc[mi][ni] = __builtin_amdgcn_mfma_f32_16x16x32_bf16(a[mi], bfr[ni], acc[mi][ni], 0, 0, 0);
        __syncthreads();
    }
#pragma unroll
    for (int mi = 0; mi < 4; ++mi) {
#pragma unroll
        for (int r = 0; r < 4; ++r) {
            int m = m0 + wm + mi * 16 + quad * 4 + r;   // n
            short* crow = skipT + (((size_t)((b << 10) + m)) << 8) + s0 + wn + lrow;
#pragma unroll
            for (int ni = 0; ni < 4; ++ni) {
                int col = s0 + wn + lrow + ni * 16;
                crow[ni * 16] = f2bf(fmaxf(acc[mi][ni][r] + sbcat[col], 0.f));
            }
        }
    }
}

// ---------------- end1 MFMA: y1[b][e][n] = relu(e1w @ skipT + e1b) bf16 ------
__global__ __launch_bounds__(256) void end1_mfma(const short* __restrict__ skipT,
                                                 const short* __restrict__ e1wb,
                                                 const float* __restrict__ e1b,
                                                 short* __restrict__ y1) {
    __shared__ __align__(16) short As[128 * 32];
    __shared__ __align__(16) short Bs[128 * 32];
    int tid = threadIdx.x;
    int wave = tid >> 6, lane = tid & 63;
    int n0 = blockIdx.x * 128;
    int m0 = blockIdx.y * 128;   // e rows
    int b = blockIdx.z;

    int idx0 = wave * 128 + lane;
    int rowS0 = idx0 >> 2, colS0 = (idx0 & 3) * 8;
    int idx1 = idx0 + 64;
    int rowS1 = idx1 >> 2, colS1 = (idx1 & 3) * 8;
    const short* gA0 = e1wb + ((size_t)(m0 + rowS0) << 8) + colS0;
    const short* gA1 = e1wb + ((size_t)(m0 + rowS1) << 8) + colS1;
    const short* gB0 = skipT + (((size_t)((b << 10) + n0 + rowS0)) << 8) + colS0;
    const short* gB1 = skipT + (((size_t)((b << 10) + n0 + rowS1)) << 8) + colS1;
    short* ldsA0 = As + wave * 1024;
    short* ldsA1 = As + wave * 1024 + 512;
    short* ldsB0 = Bs + wave * 1024;
    short* ldsB1 = Bs + wave * 1024 + 512;

    int wm = (wave & 1) * 64, wn = (wave >> 1) * 64;
    int quad = lane >> 4, lrow = lane & 15;
    const short* pa = As + (wm + lrow) * 32 + quad * 8;
    const short* pb = Bs + (wn + lrow) * 32 + quad * 8;

    f32x4 acc[4][4] = {};
    for (int kk = 0; kk < 256; kk += 32) {
        GLOAD16(gA0 + kk, ldsA0);
        GLOAD16(gA1 + kk, ldsA1);
        GLOAD16(gB0 + kk, ldsB0);
        GLOAD16(gB1 + kk, ldsB1);
        __syncthreads();
        bf16x8 a[4], bfr[4];
#pragma unroll
        for (int i = 0; i < 4; ++i) {
            a[i] = *(const bf16x8*)(pa + i * 16 * 32);
            bfr[i] = *(const bf16x8*)(pb + i * 16 * 32);
        }
#pragma unroll
        for (int mi = 0; mi < 4; ++mi)
#pragma unroll
            for (int ni = 0; ni < 4; ++ni)
                acc[mi][ni] = __builtin_amdgcn_mfma_f32_16x16x32_bf16(a[mi], bfr[ni], acc[mi][ni], 0, 0, 0);
        __syncthreads();
    }
#pragma unroll
    for (int mi = 0; mi < 4; ++mi) {
#pragma unroll
        for (int r = 0; r < 4; ++r) {
            int e = m0 + wm + mi * 16 + quad * 4 + r;
            float bias = e1b[e];
            short* crow = y1 + (((size_t)(b * 512 + e)) << 10) + n0 + wn + lrow;
#pragma unroll
            for (int ni = 0; ni < 4; ++ni)
                crow[ni * 16] = f2bf(fmaxf(acc[mi][ni][r] + bias, 0.f));
        }
    }
}

// ---------------- end2: out[b,n,o] = W2 @ y1 + b2 ---------------------------
__global__ void end2_kernel(const short* __restrict__ y1, const float* __restrict__ w2,
                            const float* __restrict__ b2, float* __restrict__ out) {
    __shared__ float sw[12][512];
    int tid = threadIdx.x;
    for (int idx = tid; idx < 6144; idx += 256) sw[idx >> 9][idx & 511] = w2[idx];
    __syncthreads();
    int n = blockIdx.x * 256 + tid;
    int bb = blockIdx.y;
    float acc[12];
#pragma unroll
    for (int o = 0; o < 12; ++o) acc[o] = b2[o];
    for (int e = 0; e < 512; ++e) {
        float y = bf2f(y1[(((size_t)(bb * 512 + e)) << 10) + n]);
#pragma unroll
        for (int o = 0; o < 12; ++o) acc[o] += sw[o][e] * y;
    }
#pragma unroll
    for (int o = 0; o < 12; ++o) out[((size_t)(bb * NNODE + n)) * 12 + o] = acc[o];
}

extern "C" void kernel_launch(void* const* d_in, const int* in_sizes, int n_in,
                              void* d_out, int out_size, void* d_ws, size_t ws_size,
                              hipStream_t stream) {
    const float* x       = (const float*)d_in[0];
    const float* emb     = (const float*)d_in[1];
    const float* start_w = (const float*)d_in[2];
    const float* start_b = (const float*)d_in[3];
    const float* tcn_w   = (const float*)d_in[4];
    const float* tcn_b   = (const float*)d_in[5];
    const float* skip_w  = (const float*)d_in[6];
    const float* skip_b  = (const float*)d_in[7];
    const float* gcn_w   = (const float*)d_in[8];
    const float* gcn_b   = (const float*)d_in[9];
    const float* bn_g    = (const float*)d_in[10];
    const float* bn_b    = (const float*)d_in[11];
    const float* bn_m    = (const float*)d_in[12];
    const float* bn_v    = (const float*)d_in[13];
    const float* e1w     = (const float*)d_in[14];
    const float* e1b     = (const float*)d_in[15];
    const float* e2w     = (const float*)d_in[16];
    const float* e2b     = (const float*)d_in[17];
    float* out = (float*)d_out;

    char* wsb = (char*)d_ws;
    short* adpT  = (short*)(wsb);                    // 2,097,152
    float* mx    = (float*)(wsb + 2097152u);         // 4,096
    float* inv   = (float*)(wsb + 2101248u);         // 4,096
    float* h     = (float*)(wsb + 2105344u);         // 27,262,976
    short* gm    = (short*)(wsb + 29368320u);        // 12,582,912 (max Lt=12)
    short* g12   = (short*)(wsb + 41951232u);        // 8,388,608
    short* wcat  = (short*)(wsb + 50339840u);        // 131,072
    float* sbcat = (float*)(wsb + 50470912u);        // 1,024
    short* e1wb  = (short*)(wsb + 50471936u);        // 262,144
    short* skipT = (short*)(wsb + 50734080u);        // 8,388,608
    short* y1    = (short*)(wsb + 59122688u);        // 16,777,216

    adp_stats<<<dim3(1024), dim3(256), 0, stream>>>(emb, mx, inv);
    adpT_kernel<<<dim3(1024), dim3(256), 0, stream>>>(emb, mx, inv, adpT);
    start_kernel<<<dim3(4, 13, 16), dim3(256), 0, stream>>>(x, start_w, start_b, h);
    repack_kernel<<<dim3(768), dim3(256), 0, stream>>>(skip_w, skip_b, e1w, wcat, sbcat, e1wb);

    const int dil[8] = {1, 2, 1, 2, 1, 2, 1, 2};
    const int t0s[8] = {1, 3, 4, 6, 7, 9, 10, 12};
    for (int i = 0; i < 8; ++i) {
        int d = dil[i];
        int t0 = t0s[i];
        int Lt = 13 - t0;
        tcn_mix_kernel<<<dim3(4, Lt, 16), dim3(256), 0, stream>>>(
            h, gm, g12, tcn_w + i * 2048, tcn_b + i * 32, gcn_w + i * 1024,
            d, t0, Lt, i);
        diff_fused<<<dim3(8, 4 * Lt), dim3(256), 0, stream>>>(
            gm, adpT, h, gcn_b + i * 32,
            bn_g + i * 32, bn_b + i * 32, bn_m + i * 32, bn_v + i * 32, t0, Lt);
    }

    skip_mfma<<<dim3(2, 8, 16), dim3(256), 0, stream>>>(g12, wcat, sbcat, skipT);
    end1_mfma<<<dim3(8, 4, 16), dim3(256), 0, stream>>>(skipT, e1wb, e1b, y1);
    end2_kernel<<<dim3(4, 16), dim3(256), 0, stream>>>(y1, e2w, e2b, out);
}

// Round 4
// 608.845 us; speedup vs baseline: 3.9048x; 1.1249x over previous
//
#include <hip/hip_runtime.h>
#include <math.h>

// GraphWaveNet forward, MI355X. Round 4:
//  - LDS xor-swizzle (2-way/free bank access on ds_read_b128 fragments)
//  - BK=64 K-loop (half the barriers) in diff/skip/end1 MFMA kernels
//  - end2 parallelized (e-split + LDS reduce)
// Layouts:
//   h    : [B=16, C=32, t=13, N=1024] fp32 (residual stream, in place)
//   gm   : [m=bc*Lt+tt][N] bf16 compact per layer (mixed gated output)
//   g12  : [b][n][256] bf16 ; adpT : [w][v] bf16
//   skipT: [b][n][s=256] bf16 ; y1 : [b][e=512][n] bf16 ; out [B,N,O] fp32

#define NBATCH 16
#define LLEN 13
#define NNODE 1024

typedef __attribute__((ext_vector_type(8))) short bf16x8;
typedef __attribute__((ext_vector_type(4))) float f32x4;

#define GLOAD16(gp, lp) __builtin_amdgcn_global_load_lds( \
    (const __attribute__((address_space(1))) void*)(gp), \
    (__attribute__((address_space(3))) void*)(lp), 16, 0, 0)

static __device__ inline short f2bf(float x) {
    union { float f; unsigned u; } v; v.f = x;
    unsigned r = v.u + 0x7FFFu + ((v.u >> 16) & 1u);
    return (short)(r >> 16);
}
static __device__ inline float bf2f(short x) {
    union { unsigned u; float f; } v; v.u = ((unsigned)(unsigned short)x) << 16;
    return v.f;
}

// ---------------- adjacency stats: per-row (v) max and 1/sum ----------------
__global__ void adp_stats(const float* __restrict__ emb, float* __restrict__ mx,
                          float* __restrict__ inv) {
    int v = blockIdx.x;
    int tid = threadIdx.x;
    __shared__ float red[256];
    float ev[10];
#pragma unroll
    for (int k = 0; k < 10; ++k) ev[k] = emb[v * 10 + k];
    float sc[4];
#pragma unroll
    for (int j = 0; j < 4; ++j) {
        int w = tid + j * 256;
        float s = 0.f;
#pragma unroll
        for (int k = 0; k < 10; ++k) s += ev[k] * emb[w * 10 + k];
        sc[j] = fmaxf(s, 0.f);
    }
    float m = fmaxf(fmaxf(sc[0], sc[1]), fmaxf(sc[2], sc[3]));
    red[tid] = m;
    __syncthreads();
    for (int s = 128; s > 0; s >>= 1) {
        if (tid < s) red[tid] = fmaxf(red[tid], red[tid + s]);
        __syncthreads();
    }
    m = red[0];
    __syncthreads();
    float sum = 0.f;
#pragma unroll
    for (int j = 0; j < 4; ++j) sum += __expf(sc[j] - m);
    red[tid] = sum;
    __syncthreads();
    for (int s = 128; s > 0; s >>= 1) {
        if (tid < s) red[tid] += red[tid + s];
        __syncthreads();
    }
    if (tid == 0) { mx[v] = m; inv[v] = 1.f / red[0]; }
}

// ---------------- adpT[w][v] = softmax_v(relu(E E^T))[v][w] bf16 ------------
__global__ void adpT_kernel(const float* __restrict__ emb, const float* __restrict__ mx,
                            const float* __restrict__ inv, short* __restrict__ adpT) {
    int w = blockIdx.x;
    int tid = threadIdx.x;
    __shared__ float ew[10];
    if (tid < 10) ew[tid] = emb[w * 10 + tid];
    __syncthreads();
#pragma unroll
    for (int j = 0; j < 4; ++j) {
        int v = tid + j * 256;
        float s = 0.f;
#pragma unroll
        for (int k = 0; k < 10; ++k) s += ew[k] * emb[v * 10 + k];
        s = fmaxf(s, 0.f);
        adpT[w * 1024 + v] = f2bf(__expf(s - mx[v]) * inv[v]);
    }
}

// ---------------- start 1x1 conv: x[B,L,N,2] -> h[B,R,t,N] fp32 -------------
__global__ void start_kernel(const float* __restrict__ x, const float* __restrict__ w,
                             const float* __restrict__ b, float* __restrict__ h) {
    int n = blockIdx.x * 256 + threadIdx.x;
    int t = blockIdx.y;
    int bb = blockIdx.z;
    float2 xv = *(const float2*)(x + (size_t)((bb * LLEN + t) * NNODE + n) * 2);
#pragma unroll
    for (int r = 0; r < 32; ++r) {
        h[((bb * 32 + r) * LLEN + t) * NNODE + n] = w[r * 2] * xv.x + w[r * 2 + 1] * xv.y + b[r];
    }
}

// ---------------- weight repack: W_cat/sb_cat (skip) + e1w bf16 -------------
__global__ void repack_kernel(const float* __restrict__ skip_w, const float* __restrict__ skip_b,
                              const float* __restrict__ e1w, short* __restrict__ wcat,
                              float* __restrict__ sbcat, short* __restrict__ e1wb) {
    int idx = blockIdx.x * 256 + threadIdx.x;
    if (idx < 65536) {
        int s = idx >> 8, k = idx & 255, i = k >> 5, c = k & 31;
        wcat[idx] = f2bf(skip_w[(i * 256 + s) * 32 + c]);
    } else {
        int j = idx - 65536;
        e1wb[j] = f2bf(e1w[j]);
    }
    if (idx < 256) {
        float s = 0.f;
#pragma unroll
        for (int i = 0; i < 8; ++i) s += skip_b[i * 256 + idx];
        sbcat[idx] = s;
    }
}

// ---------------- TCN conv + gating + gcn channel-mix -> gm bf16 -------------
__global__ void tcn_mix_kernel(const float* __restrict__ h, short* __restrict__ gm,
                               short* __restrict__ g12,
                               const float* __restrict__ w, const float* __restrict__ bias,
                               const float* __restrict__ gcnw,
                               int d, int t0, int Lt, int li) {
    __shared__ float sw0[32][32], sw1[32][32], sgw[32][32], sb[32];
    int tid = threadIdx.x;
    for (int idx = tid; idx < 1024; idx += 256) {
        int o = idx >> 5, c = idx & 31;
        sw0[o][c] = w[idx * 2];
        sw1[o][c] = w[idx * 2 + 1];
        sgw[o][c] = gcnw[idx];
    }
    if (tid < 32) sb[tid] = bias[tid];
    __syncthreads();
    int n = blockIdx.x * 256 + tid;
    int tt = blockIdx.y;
    int t = t0 + tt;
    int bb = blockIdx.z;
    const float* hb = h + (((size_t)(bb * 32 * LLEN + t)) << 10) + n;
    float hp[32], hc[32];
#pragma unroll
    for (int c = 0; c < 32; ++c) {
        hp[c] = hb[(size_t)((c * LLEN - d) << 10)];
        hc[c] = hb[(size_t)((c * LLEN) << 10)];
    }
    float gv[32];
    for (int o = 0; o < 32; ++o) {
        float a = sb[o];
#pragma unroll
        for (int c = 0; c < 32; ++c) a += sw0[o][c] * hp[c] + sw1[o][c] * hc[c];
        a = fminf(fmaxf(a, -25.f), 25.f);
        float e = __expf(-a);
        float e2 = e * e;
        gv[o] = (1.f - e2) / ((1.f + e2) * (1.f + e));  // tanh(a)*sigmoid(a)
    }
    if (t == 12) {
        short* gp = g12 + (((size_t)(bb << 10) + n) << 8) + li * 32;
#pragma unroll
        for (int c = 0; c < 32; ++c) gp[c] = f2bf(gv[c]);
    }
    for (int o = 0; o < 32; ++o) {
        float a = 0.f;
#pragma unroll
        for (int c = 0; c < 32; ++c) a += sgw[o][c] * gv[c];
        gm[(((size_t)((bb * 32 + o) * Lt + tt)) << 10) + n] = f2bf(a);
    }
}

// ======================= MFMA GEMM core pieces ==============================
// 128x128 tile, BK=64, 4 waves (2x2 of 64x64), xor-swizzled LDS.
// LDS row = 64 shorts (128 B); chunk pos p in [0,8); global col group =
// p ^ ((row>>1)&7) so fragment reads are 2-way bank aliased (free).

// ---------------- diffusion MFMA + fused gcn epilogue ------------------------
__global__ __launch_bounds__(256) void diff_fused(const short* __restrict__ gm,
                                                  const short* __restrict__ adpT,
                                                  float* __restrict__ h,
                                                  const float* __restrict__ gb,
                                                  const float* __restrict__ bng,
                                                  const float* __restrict__ bnb,
                                                  const float* __restrict__ bnm,
                                                  const float* __restrict__ bnv,
                                                  int t0, int Lt) {
    __shared__ __align__(16) short As[128 * 64];
    __shared__ __align__(16) short Bs[128 * 64];
    __shared__ float sgb[32], sinv[32], smean[32], sbeta[32];
    int tid = threadIdx.x;
    int wave = tid >> 6, lane = tid & 63;
    int n0 = blockIdx.x * 128;
    int m0 = blockIdx.y * 128;
    if (tid < 32) {
        sgb[tid] = gb[tid];
        sinv[tid] = bng[tid] * rsqrtf(bnv[tid] + 1e-5f);
        smean[tid] = bnm[tid];
        sbeta[tid] = bnb[tid];
    }

    const short* srcA[4]; const short* srcB[4];
    short* dstA[4]; short* dstB[4];
#pragma unroll
    for (int j = 0; j < 4; ++j) {
        int slot = j * 256 + wave * 64 + lane;
        int row = slot >> 3, p = slot & 7;
        int col = (p ^ ((row >> 1) & 7)) * 8;
        srcA[j] = gm + (((size_t)(m0 + row)) << 10) + col;
        srcB[j] = adpT + (((size_t)(n0 + row)) << 10) + col;
        dstA[j] = As + (j * 256 + wave * 64) * 8;
        dstB[j] = Bs + (j * 256 + wave * 64) * 8;
    }

    int wm = (wave & 1) * 64, wn = (wave >> 1) * 64;
    int quad = lane >> 4, lrow = lane & 15;
    const short* paw = As + (wm + lrow) * 64;
    const short* pbw = Bs + (wn + lrow) * 64;
    int off0 = ((quad) ^ ((lrow >> 1) & 7)) * 8;
    int off1 = ((4 + quad) ^ ((lrow >> 1) & 7)) * 8;

    f32x4 acc[4][4] = {};
    for (int kk = 0; kk < 1024; kk += 64) {
#pragma unroll
        for (int j = 0; j < 4; ++j) {
            GLOAD16(srcA[j] + kk, dstA[j]);
            GLOAD16(srcB[j] + kk, dstB[j]);
        }
        __syncthreads();
#pragma unroll
        for (int ks = 0; ks < 2; ++ks) {
            int off = ks ? off1 : off0;
            bf16x8 a[4], b[4];
#pragma unroll
            for (int i = 0; i < 4; ++i) {
                a[i] = *(const bf16x8*)(paw + i * 16 * 64 + off);
                b[i] = *(const bf16x8*)(pbw + i * 16 * 64 + off);
            }
#pragma unroll
            for (int mi = 0; mi < 4; ++mi)
#pragma unroll
                for (int ni = 0; ni < 4; ++ni)
                    acc[mi][ni] = __builtin_amdgcn_mfma_f32_16x16x32_bf16(a[mi], b[ni], acc[mi][ni], 0, 0, 0);
        }
        __syncthreads();
    }
    // epilogue: C/D col = lane&15, row = quad*4 + reg
#pragma unroll
    for (int mi = 0; mi < 4; ++mi) {
#pragma unroll
        for (int r = 0; r < 4; ++r) {
            int m = m0 + wm + mi * 16 + quad * 4 + r;
            unsigned bc = (unsigned)m / (unsigned)Lt;
            int tt = m - (int)bc * Lt;
            int c = bc & 31;
            float invv = sinv[c], meanv = smean[c], betav = sbeta[c], gbv = sgb[c];
            float* crow = h + (((size_t)(bc * LLEN + t0 + tt)) << 10) + n0 + wn + lrow;
#pragma unroll
            for (int ni = 0; ni < 4; ++ni) {
                float v = fmaxf(acc[mi][ni][r] + gbv, 0.f) + crow[ni * 16];
                crow[ni * 16] = (v - meanv) * invv + betav;
            }
        }
    }
}

// ---------------- skip GEMM: skipT[b][n][s] = relu(Wcat @ g12 + sbcat) bf16 --
__global__ __launch_bounds__(256) void skip_mfma(const short* __restrict__ g12,
                                                 const short* __restrict__ wcat,
                                                 const float* __restrict__ sbcat,
                                                 short* __restrict__ skipT) {
    __shared__ __align__(16) short As[128 * 64];
    __shared__ __align__(16) short Bs[128 * 64];
    int tid = threadIdx.x;
    int wave = tid >> 6, lane = tid & 63;
    int s0 = blockIdx.x * 128;
    int m0 = blockIdx.y * 128;   // n rows
    int b = blockIdx.z;

    const short* srcA[4]; const short* srcB[4];
    short* dstA[4]; short* dstB[4];
#pragma unroll
    for (int j = 0; j < 4; ++j) {
        int slot = j * 256 + wave * 64 + lane;
        int row = slot >> 3, p = slot & 7;
        int col = (p ^ ((row >> 1) & 7)) * 8;
        srcA[j] = g12 + (((size_t)((b << 10) + m0 + row)) << 8) + col;
        srcB[j] = wcat + (((size_t)(s0 + row)) << 8) + col;
        dstA[j] = As + (j * 256 + wave * 64) * 8;
        dstB[j] = Bs + (j * 256 + wave * 64) * 8;
    }

    int wm = (wave & 1) * 64, wn = (wave >> 1) * 64;
    int quad = lane >> 4, lrow = lane & 15;
    const short* paw = As + (wm + lrow) * 64;
    const short* pbw = Bs + (wn + lrow) * 64;
    int off0 = ((quad) ^ ((lrow >> 1) & 7)) * 8;
    int off1 = ((4 + quad) ^ ((lrow >> 1) & 7)) * 8;

    f32x4 acc[4][4] = {};
    for (int kk = 0; kk < 256; kk += 64) {
#pragma unroll
        for (int j = 0; j < 4; ++j) {
            GLOAD16(srcA[j] + kk, dstA[j]);
            GLOAD16(srcB[j] + kk, dstB[j]);
        }
        __syncthreads();
#pragma unroll
        for (int ks = 0; ks < 2; ++ks) {
            int off = ks ? off1 : off0;
            bf16x8 a[4], b[4];
#pragma unroll
            for (int i = 0; i < 4; ++i) {
                a[i] = *(const bf16x8*)(paw + i * 16 * 64 + off);
                b[i] = *(const bf16x8*)(pbw + i * 16 * 64 + off);
            }
#pragma unroll
            for (int mi = 0; mi < 4; ++mi)
#pragma unroll
                for (int ni = 0; ni < 4; ++ni)
                    acc[mi][ni] = __builtin_amdgcn_mfma_f32_16x16x32_bf16(a[mi], b[ni], acc[mi][ni], 0, 0, 0);
        }
        __syncthreads();
    }
#pragma unroll
    for (int mi = 0; mi < 4; ++mi) {
#pragma unroll
        for (int r = 0; r < 4; ++r) {
            int m = m0 + wm + mi * 16 + quad * 4 + r;   // n
            short* crow = skipT + (((size_t)((b << 10) + m)) << 8) + s0 + wn + lrow;
#pragma unroll
            for (int ni = 0; ni < 4; ++ni) {
                int col = s0 + wn + lrow + ni * 16;
                crow[ni * 16] = f2bf(fmaxf(acc[mi][ni][r] + sbcat[col], 0.f));
            }
        }
    }
}

// ---------------- end1 MFMA: y1[b][e][n] = relu(e1w @ skipT + e1b) bf16 ------
__global__ __launch_bounds__(256) void end1_mfma(const short* __restrict__ skipT,
                                                 const short* __restrict__ e1wb,
                                                 const float* __restrict__ e1b,
                                                 short* __restrict__ y1) {
    __shared__ __align__(16) short As[128 * 64];
    __shared__ __align__(16) short Bs[128 * 64];
    int tid = threadIdx.x;
    int wave = tid >> 6, lane = tid & 63;
    int n0 = blockIdx.x * 128;
    int m0 = blockIdx.y * 128;   // e rows
    int b = blockIdx.z;

    const short* srcA[4]; const short* srcB[4];
    short* dstA[4]; short* dstB[4];
#pragma unroll
    for (int j = 0; j < 4; ++j) {
        int slot = j * 256 + wave * 64 + lane;
        int row = slot >> 3, p = slot & 7;
        int col = (p ^ ((row >> 1) & 7)) * 8;
        srcA[j] = e1wb + (((size_t)(m0 + row)) << 8) + col;
        srcB[j] = skipT + (((size_t)((b << 10) + n0 + row)) << 8) + col;
        dstA[j] = As + (j * 256 + wave * 64) * 8;
        dstB[j] = Bs + (j * 256 + wave * 64) * 8;
    }

    int wm = (wave & 1) * 64, wn = (wave >> 1) * 64;
    int quad = lane >> 4, lrow = lane & 15;
    const short* paw = As + (wm + lrow) * 64;
    const short* pbw = Bs + (wn + lrow) * 64;
    int off0 = ((quad) ^ ((lrow >> 1) & 7)) * 8;
    int off1 = ((4 + quad) ^ ((lrow >> 1) & 7)) * 8;

    f32x4 acc[4][4] = {};
    for (int kk = 0; kk < 256; kk += 64) {
#pragma unroll
        for (int j = 0; j < 4; ++j) {
            GLOAD16(srcA[j] + kk, dstA[j]);
            GLOAD16(srcB[j] + kk, dstB[j]);
        }
        __syncthreads();
#pragma unroll
        for (int ks = 0; ks < 2; ++ks) {
            int off = ks ? off1 : off0;
            bf16x8 a[4], b[4];
#pragma unroll
            for (int i = 0; i < 4; ++i) {
                a[i] = *(const bf16x8*)(paw + i * 16 * 64 + off);
                b[i] = *(const bf16x8*)(pbw + i * 16 * 64 + off);
            }
#pragma unroll
            for (int mi = 0; mi < 4; ++mi)
#pragma unroll
                for (int ni = 0; ni < 4; ++ni)
                    acc[mi][ni] = __builtin_amdgcn_mfma_f32_16x16x32_bf16(a[mi], b[ni], acc[mi][ni], 0, 0, 0);
        }
        __syncthreads();
    }
#pragma unroll
    for (int mi = 0; mi < 4; ++mi) {
#pragma unroll
        for (int r = 0; r < 4; ++r) {
            int e = m0 + wm + mi * 16 + quad * 4 + r;
            float bias = e1b[e];
            short* crow = y1 + (((size_t)(b * 512 + e)) << 10) + n0 + wn + lrow;
#pragma unroll
            for (int ni = 0; ni < 4; ++ni)
                crow[ni * 16] = f2bf(fmaxf(acc[mi][ni][r] + bias, 0.f));
        }
    }
}

// ---------------- end2: out[b,n,o] = W2 @ y1 + b2 (parallel e-split) --------
__global__ __launch_bounds__(256) void end2_kernel(const short* __restrict__ y1,
                                                   const float* __restrict__ w2,
                                                   const float* __restrict__ b2,
                                                   float* __restrict__ out) {
    __shared__ float sw[12][512];
    __shared__ float ps[4][12][128];
    int tid = threadIdx.x;
    for (int idx = tid; idx < 6144; idx += 256) sw[idx >> 9][idx & 511] = w2[idx];
    __syncthreads();
    int n0 = blockIdx.x * 128;
    int bb = blockIdx.y;
    int nl = (tid & 63) * 2;
    int ec = tid >> 6;
    float acc0[12], acc1[12];
#pragma unroll
    for (int o = 0; o < 12; ++o) { acc0[o] = 0.f; acc1[o] = 0.f; }
    const short* yb = y1 + (((size_t)(bb * 512 + ec * 128)) << 10) + n0 + nl;
    for (int e = 0; e < 128; ++e) {
        ushort2 yv = *(const ushort2*)(yb + ((size_t)e << 10));
        float v0 = bf2f((short)yv.x), v1 = bf2f((short)yv.y);
        const float* we = &sw[0][ec * 128 + e];
#pragma unroll
        for (int o = 0; o < 12; ++o) {
            float wv = we[o * 512];
            acc0[o] += wv * v0;
            acc1[o] += wv * v1;
        }
    }
#pragma unroll
    for (int o = 0; o < 12; ++o) {
        ps[ec][o][nl] = acc0[o];
        ps[ec][o][nl + 1] = acc1[o];
    }
    __syncthreads();
    for (int idx = tid; idx < 1536; idx += 256) {
        int o = idx >> 7, nn = idx & 127;
        float s = b2[o] + ps[0][o][nn] + ps[1][o][nn] + ps[2][o][nn] + ps[3][o][nn];
        out[((size_t)(bb * NNODE + n0 + nn)) * 12 + o] = s;
    }
}

extern "C" void kernel_launch(void* const* d_in, const int* in_sizes, int n_in,
                              void* d_out, int out_size, void* d_ws, size_t ws_size,
                              hipStream_t stream) {
    const float* x       = (const float*)d_in[0];
    const float* emb     = (const float*)d_in[1];
    const float* start_w = (const float*)d_in[2];
    const float* start_b = (const float*)d_in[3];
    const float* tcn_w   = (const float*)d_in[4];
    const float* tcn_b   = (const float*)d_in[5];
    const float* skip_w  = (const float*)d_in[6];
    const float* skip_b  = (const float*)d_in[7];
    const float* gcn_w   = (const float*)d_in[8];
    const float* gcn_b   = (const float*)d_in[9];
    const float* bn_g    = (const float*)d_in[10];
    const float* bn_b    = (const float*)d_in[11];
    const float* bn_m    = (const float*)d_in[12];
    const float* bn_v    = (const float*)d_in[13];
    const float* e1w     = (const float*)d_in[14];
    const float* e1b     = (const float*)d_in[15];
    const float* e2w     = (const float*)d_in[16];
    const float* e2b     = (const float*)d_in[17];
    float* out = (float*)d_out;

    char* wsb = (char*)d_ws;
    short* adpT  = (short*)(wsb);                    // 2,097,152
    float* mx    = (float*)(wsb + 2097152u);         // 4,096
    float* inv   = (float*)(wsb + 2101248u);         // 4,096
    float* h     = (float*)(wsb + 2105344u);         // 27,262,976
    short* gm    = (short*)(wsb + 29368320u);        // 12,582,912 (max Lt=12)
    short* g12   = (short*)(wsb + 41951232u);        // 8,388,608
    short* wcat  = (short*)(wsb + 50339840u);        // 131,072
    float* sbcat = (float*)(wsb + 50470912u);        // 1,024
    short* e1wb  = (short*)(wsb + 50471936u);        // 262,144
    short* skipT = (short*)(wsb + 50734080u);        // 8,388,608
    short* y1    = (short*)(wsb + 59122688u);        // 16,777,216

    adp_stats<<<dim3(1024), dim3(256), 0, stream>>>(emb, mx, inv);
    adpT_kernel<<<dim3(1024), dim3(256), 0, stream>>>(emb, mx, inv, adpT);
    start_kernel<<<dim3(4, 13, 16), dim3(256), 0, stream>>>(x, start_w, start_b, h);
    repack_kernel<<<dim3(768), dim3(256), 0, stream>>>(skip_w, skip_b, e1w, wcat, sbcat, e1wb);

    const int dil[8] = {1, 2, 1, 2, 1, 2, 1, 2};
    const int t0s[8] = {1, 3, 4, 6, 7, 9, 10, 12};
    for (int i = 0; i < 8; ++i) {
        int d = dil[i];
        int t0 = t0s[i];
        int Lt = 13 - t0;
        tcn_mix_kernel<<<dim3(4, Lt, 16), dim3(256), 0, stream>>>(
            h, gm, g12, tcn_w + i * 2048, tcn_b + i * 32, gcn_w + i * 1024,
            d, t0, Lt, i);
        diff_fused<<<dim3(8, 4 * Lt), dim3(256), 0, stream>>>(
            gm, adpT, h, gcn_b + i * 32,
            bn_g + i * 32, bn_b + i * 32, bn_m + i * 32, bn_v + i * 32, t0, Lt);
    }

    skip_mfma<<<dim3(2, 8, 16), dim3(256), 0, stream>>>(g12, wcat, sbcat, skipT);
    end1_mfma<<<dim3(8, 4, 16), dim3(256), 0, stream>>>(skipT, e1wb, e1b, y1);
    end2_kernel<<<dim3(8, 16), dim3(256), 0, stream>>>(y1, e2w, e2b, out);
}

// Round 5
// 545.780 us; speedup vs baseline: 4.3560x; 1.1156x over previous
//
#include <hip/hip_runtime.h>
#include <math.h>

// GraphWaveNet forward, MI355X. Round 5:
//  - tcn_mix: weights via wave-uniform scalar loads (no LDS), 128-thr blocks,
//    8-way n-split, dual FMA chains  (was: LDS-read-bound + grid-limited)
//  - diff_fused: 64x128 tile (2x blocks; was 1.5 blocks/CU at Lt=12)
// Layouts:
//   h    : [B=16, C=32, t=13, N=1024] fp32 (residual stream, in place)
//   gm   : [m=bc*Lt+tt][N] bf16 compact per layer (mixed gated output)
//   g12  : [b][n][256] bf16 ; adpT : [w][v] bf16
//   skipT: [b][n][s=256] bf16 ; y1 : [b][e=512][n] bf16 ; out [B,N,O] fp32

#define NBATCH 16
#define LLEN 13
#define NNODE 1024

typedef __attribute__((ext_vector_type(8))) short bf16x8;
typedef __attribute__((ext_vector_type(4))) float f32x4;

#define GLOAD16(gp, lp) __builtin_amdgcn_global_load_lds( \
    (const __attribute__((address_space(1))) void*)(gp), \
    (__attribute__((address_space(3))) void*)(lp), 16, 0, 0)

static __device__ inline short f2bf(float x) {
    union { float f; unsigned u; } v; v.f = x;
    unsigned r = v.u + 0x7FFFu + ((v.u >> 16) & 1u);
    return (short)(r >> 16);
}
static __device__ inline float bf2f(short x) {
    union { unsigned u; float f; } v; v.u = ((unsigned)(unsigned short)x) << 16;
    return v.f;
}

// ---------------- adjacency stats: per-row (v) max and 1/sum ----------------
__global__ void adp_stats(const float* __restrict__ emb, float* __restrict__ mx,
                          float* __restrict__ inv) {
    int v = blockIdx.x;
    int tid = threadIdx.x;
    __shared__ float red[256];
    float ev[10];
#pragma unroll
    for (int k = 0; k < 10; ++k) ev[k] = emb[v * 10 + k];
    float sc[4];
#pragma unroll
    for (int j = 0; j < 4; ++j) {
        int w = tid + j * 256;
        float s = 0.f;
#pragma unroll
        for (int k = 0; k < 10; ++k) s += ev[k] * emb[w * 10 + k];
        sc[j] = fmaxf(s, 0.f);
    }
    float m = fmaxf(fmaxf(sc[0], sc[1]), fmaxf(sc[2], sc[3]));
    red[tid] = m;
    __syncthreads();
    for (int s = 128; s > 0; s >>= 1) {
        if (tid < s) red[tid] = fmaxf(red[tid], red[tid + s]);
        __syncthreads();
    }
    m = red[0];
    __syncthreads();
    float sum = 0.f;
#pragma unroll
    for (int j = 0; j < 4; ++j) sum += __expf(sc[j] - m);
    red[tid] = sum;
    __syncthreads();
    for (int s = 128; s > 0; s >>= 1) {
        if (tid < s) red[tid] += red[tid + s];
        __syncthreads();
    }
    if (tid == 0) { mx[v] = m; inv[v] = 1.f / red[0]; }
}

// ---------------- adpT[w][v] = softmax_v(relu(E E^T))[v][w] bf16 ------------
__global__ void adpT_kernel(const float* __restrict__ emb, const float* __restrict__ mx,
                            const float* __restrict__ inv, short* __restrict__ adpT) {
    int w = blockIdx.x;
    int tid = threadIdx.x;
    __shared__ float ew[10];
    if (tid < 10) ew[tid] = emb[w * 10 + tid];
    __syncthreads();
#pragma unroll
    for (int j = 0; j < 4; ++j) {
        int v = tid + j * 256;
        float s = 0.f;
#pragma unroll
        for (int k = 0; k < 10; ++k) s += ew[k] * emb[v * 10 + k];
        s = fmaxf(s, 0.f);
        adpT[w * 1024 + v] = f2bf(__expf(s - mx[v]) * inv[v]);
    }
}

// ---------------- start 1x1 conv: x[B,L,N,2] -> h[B,R,t,N] fp32 -------------
__global__ void start_kernel(const float* __restrict__ x, const float* __restrict__ w,
                             const float* __restrict__ b, float* __restrict__ h) {
    int n = blockIdx.x * 256 + threadIdx.x;
    int t = blockIdx.y;
    int bb = blockIdx.z;
    float2 xv = *(const float2*)(x + (size_t)((bb * LLEN + t) * NNODE + n) * 2);
#pragma unroll
    for (int r = 0; r < 32; ++r) {
        h[((bb * 32 + r) * LLEN + t) * NNODE + n] = w[r * 2] * xv.x + w[r * 2 + 1] * xv.y + b[r];
    }
}

// ---------------- weight repack: W_cat/sb_cat (skip) + e1w bf16 -------------
__global__ void repack_kernel(const float* __restrict__ skip_w, const float* __restrict__ skip_b,
                              const float* __restrict__ e1w, short* __restrict__ wcat,
                              float* __restrict__ sbcat, short* __restrict__ e1wb) {
    int idx = blockIdx.x * 256 + threadIdx.x;
    if (idx < 65536) {
        int s = idx >> 8, k = idx & 255, i = k >> 5, c = k & 31;
        wcat[idx] = f2bf(skip_w[(i * 256 + s) * 32 + c]);
    } else {
        int j = idx - 65536;
        e1wb[j] = f2bf(e1w[j]);
    }
    if (idx < 256) {
        float s = 0.f;
#pragma unroll
        for (int i = 0; i < 8; ++i) s += skip_b[i * 256 + idx];
        sbcat[idx] = s;
    }
}

// ---------------- TCN conv + gating + gcn channel-mix -> gm bf16 -------------
// Weights read with wave-uniform indices -> scalar loads (SGPR), no LDS.
__global__ __launch_bounds__(128) void tcn_mix_kernel(
        const float* __restrict__ h, short* __restrict__ gm,
        short* __restrict__ g12,
        const float* __restrict__ w, const float* __restrict__ bias,
        const float* __restrict__ gcnw,
        int d, int t0, int Lt, int li) {
    int tid = threadIdx.x;
    int n = blockIdx.x * 128 + tid;
    int tt = blockIdx.y;
    int t = t0 + tt;
    int bb = blockIdx.z;
    const float* hb = h + (((size_t)(bb * 32 * LLEN + t)) << 10) + n;
    float hp[32], hc[32];
#pragma unroll
    for (int c = 0; c < 32; ++c) {
        hp[c] = hb[(c * LLEN - d) * 1024];
        hc[c] = hb[(c * LLEN) * 1024];
    }
    float gv[32];
#pragma unroll 2
    for (int o = 0; o < 32; ++o) {
        float a0 = bias[o], a1 = 0.f;
#pragma unroll
        for (int c = 0; c < 32; ++c) {
            a0 += w[(o * 32 + c) * 2] * hp[c];
            a1 += w[(o * 32 + c) * 2 + 1] * hc[c];
        }
        float a = fminf(fmaxf(a0 + a1, -25.f), 25.f);
        float e = __expf(-a);
        float e2 = e * e;
        gv[o] = (1.f - e2) / ((1.f + e2) * (1.f + e));  // tanh(a)*sigmoid(a)
    }
    if (t == 12) {
        short* gp = g12 + (((size_t)(bb << 10) + n) << 8) + li * 32;
#pragma unroll
        for (int c = 0; c < 32; ++c) gp[c] = f2bf(gv[c]);
    }
#pragma unroll 2
    for (int o = 0; o < 32; ++o) {
        float a = 0.f;
#pragma unroll
        for (int c = 0; c < 32; ++c) a += gcnw[o * 32 + c] * gv[c];
        gm[(((size_t)((bb * 32 + o) * Lt + tt)) << 10) + n] = f2bf(a);
    }
}

// ---------------- diffusion MFMA + fused gcn epilogue ------------------------
// 64x128 (MxN) tile, BK=64, 4 waves as 2x2 (wave tile 32x64), xor-swizzled LDS.
__global__ __launch_bounds__(256) void diff_fused(const short* __restrict__ gm,
                                                  const short* __restrict__ adpT,
                                                  float* __restrict__ h,
                                                  const float* __restrict__ gb,
                                                  const float* __restrict__ bng,
                                                  const float* __restrict__ bnb,
                                                  const float* __restrict__ bnm,
                                                  const float* __restrict__ bnv,
                                                  int t0, int Lt) {
    __shared__ __align__(16) short As[64 * 64];
    __shared__ __align__(16) short Bs[128 * 64];
    __shared__ float sgb[32], sinv[32], smean[32], sbeta[32];
    int tid = threadIdx.x;
    int wave = tid >> 6, lane = tid & 63;
    int n0 = blockIdx.x * 128;
    int m0 = blockIdx.y * 64;
    if (tid < 32) {
        sgb[tid] = gb[tid];
        sinv[tid] = bng[tid] * rsqrtf(bnv[tid] + 1e-5f);
        smean[tid] = bnm[tid];
        sbeta[tid] = bnb[tid];
    }

    const short* srcA[2]; short* dstA[2];
    const short* srcB[4]; short* dstB[4];
#pragma unroll
    for (int j = 0; j < 2; ++j) {
        int slot = j * 256 + wave * 64 + lane;
        int row = slot >> 3, p = slot & 7;
        int col = (p ^ ((row >> 1) & 7)) * 8;
        srcA[j] = gm + (((size_t)(m0 + row)) << 10) + col;
        dstA[j] = As + slot * 8;
    }
#pragma unroll
    for (int j = 0; j < 4; ++j) {
        int slot = j * 256 + wave * 64 + lane;
        int row = slot >> 3, p = slot & 7;
        int col = (p ^ ((row >> 1) & 7)) * 8;
        srcB[j] = adpT + (((size_t)(n0 + row)) << 10) + col;
        dstB[j] = Bs + slot * 8;
    }

    int wm = (wave & 1) * 32, wn = (wave >> 1) * 64;
    int quad = lane >> 4, lrow = lane & 15;
    const short* paw = As + (wm + lrow) * 64;
    const short* pbw = Bs + (wn + lrow) * 64;
    int off0 = ((quad) ^ ((lrow >> 1) & 7)) * 8;
    int off1 = ((4 + quad) ^ ((lrow >> 1) & 7)) * 8;

    f32x4 acc[2][4] = {};
    for (int kk = 0; kk < 1024; kk += 64) {
#pragma unroll
        for (int j = 0; j < 2; ++j) GLOAD16(srcA[j] + kk, dstA[j]);
#pragma unroll
        for (int j = 0; j < 4; ++j) GLOAD16(srcB[j] + kk, dstB[j]);
        __syncthreads();
#pragma unroll
        for (int ks = 0; ks < 2; ++ks) {
            int off = ks ? off1 : off0;
            bf16x8 a[2], b[4];
#pragma unroll
            for (int i = 0; i < 2; ++i) a[i] = *(const bf16x8*)(paw + i * 16 * 64 + off);
#pragma unroll
            for (int i = 0; i < 4; ++i) b[i] = *(const bf16x8*)(pbw + i * 16 * 64 + off);
#pragma unroll
            for (int mi = 0; mi < 2; ++mi)
#pragma unroll
                for (int ni = 0; ni < 4; ++ni)
                    acc[mi][ni] = __builtin_amdgcn_mfma_f32_16x16x32_bf16(a[mi], b[ni], acc[mi][ni], 0, 0, 0);
        }
        __syncthreads();
    }
    // epilogue: C/D col = lane&15, row = quad*4 + reg
#pragma unroll
    for (int mi = 0; mi < 2; ++mi) {
#pragma unroll
        for (int r = 0; r < 4; ++r) {
            int m = m0 + wm + mi * 16 + quad * 4 + r;
            unsigned bc = (unsigned)m / (unsigned)Lt;
            int tt = m - (int)bc * Lt;
            int c = bc & 31;
            float invv = sinv[c], meanv = smean[c], betav = sbeta[c], gbv = sgb[c];
            float* crow = h + (((size_t)(bc * LLEN + t0 + tt)) << 10) + n0 + wn + lrow;
#pragma unroll
            for (int ni = 0; ni < 4; ++ni) {
                float v = fmaxf(acc[mi][ni][r] + gbv, 0.f) + crow[ni * 16];
                crow[ni * 16] = (v - meanv) * invv + betav;
            }
        }
    }
}

// ---------------- skip GEMM: skipT[b][n][s] = relu(Wcat @ g12 + sbcat) bf16 --
__global__ __launch_bounds__(256) void skip_mfma(const short* __restrict__ g12,
                                                 const short* __restrict__ wcat,
                                                 const float* __restrict__ sbcat,
                                                 short* __restrict__ skipT) {
    __shared__ __align__(16) short As[128 * 64];
    __shared__ __align__(16) short Bs[128 * 64];
    int tid = threadIdx.x;
    int wave = tid >> 6, lane = tid & 63;
    int s0 = blockIdx.x * 128;
    int m0 = blockIdx.y * 128;   // n rows
    int b = blockIdx.z;

    const short* srcA[4]; const short* srcB[4];
    short* dstA[4]; short* dstB[4];
#pragma unroll
    for (int j = 0; j < 4; ++j) {
        int slot = j * 256 + wave * 64 + lane;
        int row = slot >> 3, p = slot & 7;
        int col = (p ^ ((row >> 1) & 7)) * 8;
        srcA[j] = g12 + (((size_t)((b << 10) + m0 + row)) << 8) + col;
        srcB[j] = wcat + (((size_t)(s0 + row)) << 8) + col;
        dstA[j] = As + (j * 256 + wave * 64) * 8;
        dstB[j] = Bs + (j * 256 + wave * 64) * 8;
    }

    int wm = (wave & 1) * 64, wn = (wave >> 1) * 64;
    int quad = lane >> 4, lrow = lane & 15;
    const short* paw = As + (wm + lrow) * 64;
    const short* pbw = Bs + (wn + lrow) * 64;
    int off0 = ((quad) ^ ((lrow >> 1) & 7)) * 8;
    int off1 = ((4 + quad) ^ ((lrow >> 1) & 7)) * 8;

    f32x4 acc[4][4] = {};
    for (int kk = 0; kk < 256; kk += 64) {
#pragma unroll
        for (int j = 0; j < 4; ++j) {
            GLOAD16(srcA[j] + kk, dstA[j]);
            GLOAD16(srcB[j] + kk, dstB[j]);
        }
        __syncthreads();
#pragma unroll
        for (int ks = 0; ks < 2; ++ks) {
            int off = ks ? off1 : off0;
            bf16x8 a[4], b[4];
#pragma unroll
            for (int i = 0; i < 4; ++i) {
                a[i] = *(const bf16x8*)(paw + i * 16 * 64 + off);
                b[i] = *(const bf16x8*)(pbw + i * 16 * 64 + off);
            }
#pragma unroll
            for (int mi = 0; mi < 4; ++mi)
#pragma unroll
                for (int ni = 0; ni < 4; ++ni)
                    acc[mi][ni] = __builtin_amdgcn_mfma_f32_16x16x32_bf16(a[mi], b[ni], acc[mi][ni], 0, 0, 0);
        }
        __syncthreads();
    }
#pragma unroll
    for (int mi = 0; mi < 4; ++mi) {
#pragma unroll
        for (int r = 0; r < 4; ++r) {
            int m = m0 + wm + mi * 16 + quad * 4 + r;   // n
            short* crow = skipT + (((size_t)((b << 10) + m)) << 8) + s0 + wn + lrow;
#pragma unroll
            for (int ni = 0; ni < 4; ++ni) {
                int col = s0 + wn + lrow + ni * 16;
                crow[ni * 16] = f2bf(fmaxf(acc[mi][ni][r] + sbcat[col], 0.f));
            }
        }
    }
}

// ---------------- end1 MFMA: y1[b][e][n] = relu(e1w @ skipT + e1b) bf16 ------
__global__ __launch_bounds__(256) void end1_mfma(const short* __restrict__ skipT,
                                                 const short* __restrict__ e1wb,
                                                 const float* __restrict__ e1b,
                                                 short* __restrict__ y1) {
    __shared__ __align__(16) short As[128 * 64];
    __shared__ __align__(16) short Bs[128 * 64];
    int tid = threadIdx.x;
    int wave = tid >> 6, lane = tid & 63;
    int n0 = blockIdx.x * 128;
    int m0 = blockIdx.y * 128;   // e rows
    int b = blockIdx.z;

    const short* srcA[4]; const short* srcB[4];
    short* dstA[4]; short* dstB[4];
#pragma unroll
    for (int j = 0; j < 4; ++j) {
        int slot = j * 256 + wave * 64 + lane;
        int row = slot >> 3, p = slot & 7;
        int col = (p ^ ((row >> 1) & 7)) * 8;
        srcA[j] = e1wb + (((size_t)(m0 + row)) << 8) + col;
        srcB[j] = skipT + (((size_t)((b << 10) + n0 + row)) << 8) + col;
        dstA[j] = As + (j * 256 + wave * 64) * 8;
        dstB[j] = Bs + (j * 256 + wave * 64) * 8;
    }

    int wm = (wave & 1) * 64, wn = (wave >> 1) * 64;
    int quad = lane >> 4, lrow = lane & 15;
    const short* paw = As + (wm + lrow) * 64;
    const short* pbw = Bs + (wn + lrow) * 64;
    int off0 = ((quad) ^ ((lrow >> 1) & 7)) * 8;
    int off1 = ((4 + quad) ^ ((lrow >> 1) & 7)) * 8;

    f32x4 acc[4][4] = {};
    for (int kk = 0; kk < 256; kk += 64) {
#pragma unroll
        for (int j = 0; j < 4; ++j) {
            GLOAD16(srcA[j] + kk, dstA[j]);
            GLOAD16(srcB[j] + kk, dstB[j]);
        }
        __syncthreads();
#pragma unroll
        for (int ks = 0; ks < 2; ++ks) {
            int off = ks ? off1 : off0;
            bf16x8 a[4], b[4];
#pragma unroll
            for (int i = 0; i < 4; ++i) {
                a[i] = *(const bf16x8*)(paw + i * 16 * 64 + off);
                b[i] = *(const bf16x8*)(pbw + i * 16 * 64 + off);
            }
#pragma unroll
            for (int mi = 0; mi < 4; ++mi)
#pragma unroll
                for (int ni = 0; ni < 4; ++ni)
                    acc[mi][ni] = __builtin_amdgcn_mfma_f32_16x16x32_bf16(a[mi], b[ni], acc[mi][ni], 0, 0, 0);
        }
        __syncthreads();
    }
#pragma unroll
    for (int mi = 0; mi < 4; ++mi) {
#pragma unroll
        for (int r = 0; r < 4; ++r) {
            int e = m0 + wm + mi * 16 + quad * 4 + r;
            float bias = e1b[e];
            short* crow = y1 + (((size_t)(b * 512 + e)) << 10) + n0 + wn + lrow;
#pragma unroll
            for (int ni = 0; ni < 4; ++ni)
                crow[ni * 16] = f2bf(fmaxf(acc[mi][ni][r] + bias, 0.f));
        }
    }
}

// ---------------- end2: out[b,n,o] = W2 @ y1 + b2 (parallel e-split) --------
__global__ __launch_bounds__(256) void end2_kernel(const short* __restrict__ y1,
                                                   const float* __restrict__ w2,
                                                   const float* __restrict__ b2,
                                                   float* __restrict__ out) {
    __shared__ float sw[12][512];
    __shared__ float ps[4][12][128];
    int tid = threadIdx.x;
    for (int idx = tid; idx < 6144; idx += 256) sw[idx >> 9][idx & 511] = w2[idx];
    __syncthreads();
    int n0 = blockIdx.x * 128;
    int bb = blockIdx.y;
    int nl = (tid & 63) * 2;
    int ec = tid >> 6;
    float acc0[12], acc1[12];
#pragma unroll
    for (int o = 0; o < 12; ++o) { acc0[o] = 0.f; acc1[o] = 0.f; }
    const short* yb = y1 + (((size_t)(bb * 512 + ec * 128)) << 10) + n0 + nl;
    for (int e = 0; e < 128; ++e) {
        ushort2 yv = *(const ushort2*)(yb + ((size_t)e << 10));
        float v0 = bf2f((short)yv.x), v1 = bf2f((short)yv.y);
        const float* we = &sw[0][ec * 128 + e];
#pragma unroll
        for (int o = 0; o < 12; ++o) {
            float wv = we[o * 512];
            acc0[o] += wv * v0;
            acc1[o] += wv * v1;
        }
    }
#pragma unroll
    for (int o = 0; o < 12; ++o) {
        ps[ec][o][nl] = acc0[o];
        ps[ec][o][nl + 1] = acc1[o];
    }
    __syncthreads();
    for (int idx = tid; idx < 1536; idx += 256) {
        int o = idx >> 7, nn = idx & 127;
        float s = b2[o] + ps[0][o][nn] + ps[1][o][nn] + ps[2][o][nn] + ps[3][o][nn];
        out[((size_t)(bb * NNODE + n0 + nn)) * 12 + o] = s;
    }
}

extern "C" void kernel_launch(void* const* d_in, const int* in_sizes, int n_in,
                              void* d_out, int out_size, void* d_ws, size_t ws_size,
                              hipStream_t stream) {
    const float* x       = (const float*)d_in[0];
    const float* emb     = (const float*)d_in[1];
    const float* start_w = (const float*)d_in[2];
    const float* start_b = (const float*)d_in[3];
    const float* tcn_w   = (const float*)d_in[4];
    const float* tcn_b   = (const float*)d_in[5];
    const float* skip_w  = (const float*)d_in[6];
    const float* skip_b  = (const float*)d_in[7];
    const float* gcn_w   = (const float*)d_in[8];
    const float* gcn_b   = (const float*)d_in[9];
    const float* bn_g    = (const float*)d_in[10];
    const float* bn_b    = (const float*)d_in[11];
    const float* bn_m    = (const float*)d_in[12];
    const float* bn_v    = (const float*)d_in[13];
    const float* e1w     = (const float*)d_in[14];
    const float* e1b     = (const float*)d_in[15];
    const float* e2w     = (const float*)d_in[16];
    const float* e2b     = (const float*)d_in[17];
    float* out = (float*)d_out;

    char* wsb = (char*)d_ws;
    short* adpT  = (short*)(wsb);                    // 2,097,152
    float* mx    = (float*)(wsb + 2097152u);         // 4,096
    float* inv   = (float*)(wsb + 2101248u);         // 4,096
    float* h     = (float*)(wsb + 2105344u);         // 27,262,976
    short* gm    = (short*)(wsb + 29368320u);        // 12,582,912 (max Lt=12)
    short* g12   = (short*)(wsb + 41951232u);        // 8,388,608
    short* wcat  = (short*)(wsb + 50339840u);        // 131,072
    float* sbcat = (float*)(wsb + 50470912u);        // 1,024
    short* e1wb  = (short*)(wsb + 50471936u);        // 262,144
    short* skipT = (short*)(wsb + 50734080u);        // 8,388,608
    short* y1    = (short*)(wsb + 59122688u);        // 16,777,216

    adp_stats<<<dim3(1024), dim3(256), 0, stream>>>(emb, mx, inv);
    adpT_kernel<<<dim3(1024), dim3(256), 0, stream>>>(emb, mx, inv, adpT);
    start_kernel<<<dim3(4, 13, 16), dim3(256), 0, stream>>>(x, start_w, start_b, h);
    repack_kernel<<<dim3(768), dim3(256), 0, stream>>>(skip_w, skip_b, e1w, wcat, sbcat, e1wb);

    const int dil[8] = {1, 2, 1, 2, 1, 2, 1, 2};
    const int t0s[8] = {1, 3, 4, 6, 7, 9, 10, 12};
    for (int i = 0; i < 8; ++i) {
        int d = dil[i];
        int t0 = t0s[i];
        int Lt = 13 - t0;
        tcn_mix_kernel<<<dim3(8, Lt, 16), dim3(128), 0, stream>>>(
            h, gm, g12, tcn_w + i * 2048, tcn_b + i * 32, gcn_w + i * 1024,
            d, t0, Lt, i);
        diff_fused<<<dim3(8, 8 * Lt), dim3(256), 0, stream>>>(
            gm, adpT, h, gcn_b + i * 32,
            bn_g + i * 32, bn_b + i * 32, bn_m + i * 32, bn_v + i * 32, t0, Lt);
    }

    skip_mfma<<<dim3(2, 8, 16), dim3(256), 0, stream>>>(g12, wcat, sbcat, skipT);
    end1_mfma<<<dim3(8, 4, 16), dim3(256), 0, stream>>>(skipT, e1wb, e1b, y1);
    end2_kernel<<<dim3(8, 16), dim3(256), 0, stream>>>(y1, e2w, e2b, out);
}